// Round 10
// baseline (1212.152 us; speedup 1.0000x reference)
//
#include <hip/hip_runtime.h>
#include <stdint.h>

#define TT 256
#define NS 4
#define CH 8

typedef __attribute__((ext_vector_type(4))) float f32x4;
typedef __attribute__((ext_vector_type(8))) short s16x8;
typedef __attribute__((ext_vector_type(2))) unsigned int u32x2;

#define DEV static __device__ __forceinline__

// prepped bf16 Wih1 fragments: [dir][ntg(32)][kt(8)][lane(64)][8]
__device__ uint16_t g_W1f[2*32*8*64*8];

DEV short f2bf(float f){
  union{float f; uint32_t u;} v; v.f = f;
  uint32_t r = v.u + 0x7fffu + ((v.u>>16)&1u);
  return (short)(r>>16);
}
DEV float bf2f(uint32_t u16){
  union{uint32_t u; float f;} v; v.u = u16<<16; return v.f;
}
DEV uint32_t pk2(float a, float b){
  return (uint32_t)(uint16_t)f2bf(a) | ((uint32_t)(uint16_t)f2bf(b)<<16);
}
DEV float rcpf(float x){ return __builtin_amdgcn_rcpf(x); }
DEV float sigm(float x){ return rcpf(1.f + __expf(-x)); }
DEV float tanh_f(float x){ float e = __expf(2.f*x); return 1.f - 2.f*rcpf(e+1.f); }
DEV f32x4 MFMA(s16x8 a, s16x8 b, f32x4 c){
  return __builtin_amdgcn_mfma_f32_16x16x32_bf16(a, b, c, 0, 0, 0);
}
DEV s16x8 cvt8(const float* p){
  f32x4 a = *(const f32x4*)p;
  f32x4 b = *(const f32x4*)(p+4);
  s16x8 o;
  o[0]=f2bf(a[0]); o[1]=f2bf(a[1]); o[2]=f2bf(a[2]); o[3]=f2bf(a[3]);
  o[4]=f2bf(b[0]); o[5]=f2bf(b[1]); o[6]=f2bf(b[2]); o[7]=f2bf(b[3]);
  return o;
}
// barrier that drains LDS only (global stores/loads stay in flight)
DEV void bar_lds(){
  asm volatile("s_waitcnt lgkmcnt(0)" ::: "memory");
  __builtin_amdgcn_s_barrier();
}

// flush one step's h (NS=4 rows x 128 cols bf16) from a 4KB hbuf frame.
// hbuf swizzle: h[r][c] at byte r*256 + ((c*2) ^ (r<<4)); 64 threads, 16B each.
DEV void flush_step(const short* hb, uint16_t* __restrict__ hdst, int tp,
                    int dir, int BR, int bg, int tid){
  if (tid < 64){
    int row = tid >> 4, part = tid & 15;
    int tg = dir ? (TT-1-tp) : tp;
    s16x8 v = *(const s16x8*)((const char*)hb + row*256 + (((part ^ row)&15)<<4));
    *(s16x8*)(hdst + ((size_t)tg*BR + bg*NS + row)*256 + dir*128 + part*8) = v;
  }
}

// redistribute: lane (lk,lm) gets x[G] = acc[G][j=lk] taken from lane lm (lk=0 group)
DEV float gsel(const f32x4& a, int lm, int lk){
  float t0 = __shfl(a[0], lm);
  float t1 = __shfl(a[1], lm);
  float t2 = __shfl(a[2], lm);
  float t3 = __shfl(a[3], lm);
  float lo = (lk & 1) ? t1 : t0;
  float hi = (lk & 1) ? t3 : t2;
  return (lk & 2) ? hi : lo;
}

// ---------------- Wih1 -> bf16 B-fragment layout ----------------
__global__ __launch_bounds__(256) void prep_wih1(const float* __restrict__ Wih1)
{
  int tid = blockIdx.x*256 + threadIdx.x;   // 32768 total
  int l = tid & 63, kt = (tid>>6)&7, ntg = (tid>>9)&31, dir = (tid>>14)&1;
  int lm = l&15, lk = l>>4;
  int n = ntg*16 + lm;
  s16x8 o = cvt8(Wih1 + ((size_t)(dir*512 + n))*256 + kt*32 + lk*8);
  *(s16x8*)(&g_W1f[(size_t)tid*8]) = o;
}

// ================= BiLSTM layer 0 (LN fused; 6 -> 128/dir), NS=4 =================
__global__ __launch_bounds__(512,2) void lstm0_kernel(
    const float* __restrict__ x, const float* __restrict__ lng,
    const float* __restrict__ lnb,
    const float* __restrict__ Wih0, const float* __restrict__ Whh0,
    const float* __restrict__ bih0, const float* __restrict__ bhh0,
    uint16_t* __restrict__ h0, int nb, int BR, int b_off)
{
  const int dir = blockIdx.x / nb, bg = blockIdx.x % nb;
  const int tid = threadIdx.x, w = tid>>6, l = tid&63;
  const int lm = l&15, lk = l>>4;
  const int gb = b_off + bg*NS;

  __shared__ short hbuf[2][2048];     // 8 KB: 2 frames x 16 rows x 128 (rows 4-15 = 0)
  __shared__ short xnbf[TT*NS*8];     // 16 KB
  __shared__ short bxs[8*4*64*8];     // 32 KB: input-proj fragments per (w,G,l)

  for (int i=tid; i<4096; i+=512) ((short*)hbuf)[i] = 0;

  // LN fused staging
  #pragma unroll
  for (int it=0; it<2; ++it){
    int pr = it*512 + tid;
    int r = pr >> 8, t = pr & 255;
    const float* px = x + ((size_t)(gb+r)*TT + t)*6;
    float v[6]; float mu=0.f, var=0.f;
    #pragma unroll
    for (int d=0; d<6; ++d){ v[d]=px[d]; mu+=v[d]; }
    mu *= (1.f/6.f);
    #pragma unroll
    for (int d=0; d<6; ++d){ float dd=v[d]-mu; var+=dd*dd; }
    float rs = rsqrtf(var*(1.f/6.f) + 1e-5f);
    s16x8 vv;
    #pragma unroll
    for (int d=0; d<6; ++d) vv[d] = f2bf((v[d]-mu)*rs*lng[d] + lnb[d]);
    vv[6]=0; vv[7]=0;
    *(s16x8*)&xnbf[(t*NS + r)*8] = vv;
  }

  const int c = w*16 + lm;
  s16x8 bw[4][4];
  float biasc[4];
  #pragma unroll
  for (int G=0; G<4; ++G){
    const int n = G*128 + c;
    biasc[G] = bih0[dir*512+n] + bhh0[dir*512+n];
    #pragma unroll
    for (int kt=0; kt<4; ++kt)
      bw[G][kt] = cvt8(Whh0 + ((size_t)(dir*512+n))*128 + kt*32 + lk*8);
    s16x8 tx;
    #pragma unroll
    for (int j=0; j<8; ++j){
      int k = lk*8 + j;
      tx[j] = (k<6) ? f2bf(Wih0[(size_t)(dir*512+n)*6 + k]) : (short)0;
    }
    *(s16x8*)&bxs[((w*4+G)*64 + l)*8] = tx;
  }

  float cst = 0.f;
  __syncthreads();

  for (int t=0; t<TT; ++t){
    const int tt = dir ? (TT-1-t) : t;
    const int rd = t & 1;
    s16x8 ah[4];
    #pragma unroll
    for (int kt=0; kt<4; ++kt){
      int off = rd*4096 + lm*256 + ((kt*64 + lk*16) ^ (lm<<4));
      ah[kt] = *(const s16x8*)((const char*)hbuf + off);
    }
    s16x8 ax = {0,0,0,0,0,0,0,0};
    if (l < NS) ax = *(const s16x8*)&xnbf[(tt*NS + l)*8];

    f32x4 acc[4];
    #pragma unroll
    for (int G=0; G<4; ++G){
      f32x4 a = {0.f,0.f,0.f,0.f};
      #pragma unroll
      for (int kt=0; kt<4; ++kt) a = MFMA(ah[kt], bw[G][kt], a);
      s16x8 bx = *(const s16x8*)&bxs[((w*4+G)*64 + l)*8];
      a = MFMA(ax, bx, a);
      acc[G] = a;
    }

    float g0 = gsel(acc[0], lm, lk) + biasc[0];
    float g1 = gsel(acc[1], lm, lk) + biasc[1];
    float g2 = gsel(acc[2], lm, lk) + biasc[2];
    float g3 = gsel(acc[3], lm, lk) + biasc[3];
    float cc = sigm(g1)*cst + sigm(g0)*tanh_f(g2);
    cst = cc;
    float hv = sigm(g3)*tanh_f(cc);

    *(short*)((char*)hbuf + (rd^1)*4096 + lk*256 + ((c*2) ^ (lk<<4))) = f2bf(hv);
    if (t > 0)
      flush_step(hbuf[rd], h0, t-1, dir, BR, bg, tid);
    bar_lds();
  }
  flush_step(hbuf[0], h0, TT-1, dir, BR, bg, tid);   // h(255) sits in hbuf[0]
}

// ============ BiLSTM layer 1 (256 -> 128/dir), fused xp, NS=4, CH=8 ============
__global__ __launch_bounds__(512,2) void lstm1_kernel(
    const uint16_t* __restrict__ h0,
    const float* __restrict__ Whh1, const float* __restrict__ bih1,
    const float* __restrict__ bhh1, uint16_t* __restrict__ h1,
    int nb, int BR)
{
  const int dir = blockIdx.x / nb, bg = blockIdx.x % nb;
  const int tid = threadIdx.x, w = tid>>6, l = tid&63;
  const int lm = l&15, lk = l>>4;

  __shared__ short hbuf[2][2048];     // 8 KB
  __shared__ short abuf[32*256];      // 16 KB: CH*NS=32 rows x 256 cols, single buf
  __shared__ u32x2 xpbuf[4096];       // 32 KB: [w][G][mt(2)][lane] packed-bf16 xp

  for (int i=tid; i<4096; i+=512) ((short*)hbuf)[i] = 0;

  const int c = w*16 + lm;
  s16x8 bw[4][4];
  float biasv[4];
  #pragma unroll
  for (int G=0; G<4; ++G){
    const int n = G*128 + c;
    biasv[G] = bih1[dir*512+n] + bhh1[dir*512+n];
    #pragma unroll
    for (int kt=0; kt<4; ++kt)
      bw[G][kt] = cvt8(Whh1 + ((size_t)(dir*512+n))*128 + kt*32 + lk*8);
  }

  float cst = 0.f;
  s16x8 vst[2];

  // prologue: stage chunk 0 (rows = s*NS + b, s in [0,8), b in [0,4))
  #pragma unroll
  for (int it=0; it<2; ++it){
    int sid = it*512 + tid, row = sid>>5, sl = sid&31, s = row>>2, b = row&3;
    int tg = dir ? (TT-1-s) : s;
    vst[it] = *(const s16x8*)(h0 + ((size_t)tg*BR + bg*NS + b)*256 + sl*8);
  }
  #pragma unroll
  for (int it=0; it<2; ++it){
    int sid = it*512 + tid, row = sid>>5, sl = sid&31;
    *(s16x8*)((char*)abuf + row*512 + ((sl ^ (row&15))<<4)) = vst[it];
  }
  __syncthreads();

  for (int ch=0; ch<TT/CH; ++ch){
    // issue next chunk's loads early (land during phase A)
    if (ch < TT/CH-1){
      #pragma unroll
      for (int it=0; it<2; ++it){
        int sid = it*512 + tid, row = sid>>5, sl = sid&31, s = row>>2, b = row&3;
        int ts = (ch+1)*CH + s;
        int tg = dir ? (TT-1-ts) : ts;
        vst[it] = *(const s16x8*)(h0 + ((size_t)tg*BR + bg*NS + b)*256 + sl*8);
      }
    }

    // ---- phase A: xp for CH steps -> LDS ----
    #pragma unroll
    for (int G=0; G<4; ++G){
      f32x4 acc[2];
      #pragma unroll
      for (int mt=0; mt<2; ++mt) acc[mt] = (f32x4){biasv[G],biasv[G],biasv[G],biasv[G]};
      #pragma unroll
      for (int kt=0; kt<8; ++kt){
        s16x8 bfr = *(const s16x8*)(&g_W1f[(((size_t)(dir*32 + G*8 + w)*8 + kt)*64 + l)*8]);
        #pragma unroll
        for (int mt=0; mt<2; ++mt){
          int row = mt*16 + lm;
          s16x8 afr = *(const s16x8*)((const char*)abuf + row*512 + (((kt*4+lk) ^ (row&15))<<4));
          acc[mt] = MFMA(afr, bfr, acc[mt]);
        }
      }
      #pragma unroll
      for (int mt=0; mt<2; ++mt){
        u32x2 pw;
        pw[0] = pk2(acc[mt][0], acc[mt][1]);
        pw[1] = pk2(acc[mt][2], acc[mt][3]);
        xpbuf[((w*4+G)*2+mt)*64 + l] = pw;
      }
    }
    bar_lds();   // phase-A abuf reads + xpbuf writes complete

    // overwrite abuf with next chunk (phase B never touches abuf)
    if (ch < TT/CH-1){
      #pragma unroll
      for (int it=0; it<2; ++it){
        int sid = it*512 + tid, row = sid>>5, sl = sid&31;
        *(s16x8*)((char*)abuf + row*512 + ((sl ^ (row&15))<<4)) = vst[it];
      }
    }

    // ---- phase B: CH recurrent steps ----
    #pragma unroll
    for (int s=0; s<CH; ++s){
      const int gs = ch*CH + s;
      const int rd = gs & 1;
      // xp rows s*4+b live in xpbuf tile mt=s>>2 at lanes (s&3)*16 + lm
      const int lane2 = ((s&3)<<4) + lm;

      f32x4 acc4[4];
      #pragma unroll
      for (int G=0; G<4; ++G){
        u32x2 pw = xpbuf[((w*4+G)*2 + (s>>2))*64 + lane2];
        acc4[G] = (f32x4){bf2f(pw[0]&0xffffu), bf2f(pw[0]>>16),
                          bf2f(pw[1]&0xffffu), bf2f(pw[1]>>16)};
      }

      s16x8 ah[4];
      #pragma unroll
      for (int kt=0; kt<4; ++kt){
        int off = rd*4096 + lm*256 + ((kt*64 + lk*16) ^ (lm<<4));
        ah[kt] = *(const s16x8*)((const char*)hbuf + off);
      }
      #pragma unroll
      for (int G=0; G<4; ++G){
        #pragma unroll
        for (int kt=0; kt<4; ++kt)
          acc4[G] = MFMA(ah[kt], bw[G][kt], acc4[G]);
      }

      float g0 = gsel(acc4[0], lm, lk);
      float g1 = gsel(acc4[1], lm, lk);
      float g2 = gsel(acc4[2], lm, lk);
      float g3 = gsel(acc4[3], lm, lk);
      float cc = sigm(g1)*cst + sigm(g0)*tanh_f(g2);
      cst = cc;
      float hv = sigm(g3)*tanh_f(cc);

      *(short*)((char*)hbuf + (rd^1)*4096 + lk*256 + ((c*2) ^ (lk<<4))) = f2bf(hv);
      if (gs > 0)
        flush_step(hbuf[rd], h1, gs-1, dir, BR, bg, tid);
      bar_lds();
    }
  }
  flush_step(hbuf[0], h1, TT-1, dir, BR, bg, tid);   // h(255) sits in hbuf[0]
}

// ================= attention scores =================
__global__ __launch_bounds__(256,2) void scores_kernel(
    const uint16_t* __restrict__ h1, const float* __restrict__ Wa1,
    const float* __restrict__ ba1, const float* __restrict__ Wa2,
    const float* __restrict__ ba2, float* __restrict__ scores,
    int nbb, int BR)
{
  const int bx = blockIdx.x;
  const int t = bx / nbb, bb = (bx - t*nbb) * 64;
  const int tid = threadIdx.x, w = tid>>6, l = tid&63;
  const int lm = l&15, lk = l>>4;
  __shared__ short abuf[64*256];
  __shared__ float scred[4][64];

  #pragma unroll
  for (int it=0; it<8; ++it){
    int sid = it*256 + tid, row = sid>>5, sl = sid&31;
    s16x8 v = *(const s16x8*)(h1 + ((size_t)t*BR + bb + row)*256 + sl*8);
    *(s16x8*)((char*)abuf + row*512 + ((sl ^ (row&15))<<4)) = v;
  }

  s16x8 bwa[2][8]; float b1v[2], wa2v[2];
  #pragma unroll
  for (int nt=0; nt<2; ++nt){
    int n = w*32 + nt*16 + lm;
    b1v[nt] = ba1[n]; wa2v[nt] = Wa2[n];
    #pragma unroll
    for (int kt=0; kt<8; ++kt)
      bwa[nt][kt] = cvt8(Wa1 + (size_t)n*256 + kt*32 + lk*8);
  }
  __syncthreads();

  #pragma unroll
  for (int mt=0; mt<4; ++mt){
    f32x4 a0 = {b1v[0],b1v[0],b1v[0],b1v[0]};
    f32x4 a1 = {b1v[1],b1v[1],b1v[1],b1v[1]};
    #pragma unroll
    for (int kt=0; kt<8; ++kt){
      int row = mt*16 + lm;
      s16x8 af = *(const s16x8*)((const char*)abuf + row*512 + (((kt*4+lk) ^ (row&15))<<4));
      a0 = MFMA(af, bwa[0][kt], a0);
      a1 = MFMA(af, bwa[1][kt], a1);
    }
    #pragma unroll
    for (int j=0; j<4; ++j){
      float pj = tanh_f(a0[j])*wa2v[0] + tanh_f(a1[j])*wa2v[1];
      #pragma unroll
      for (int m=1; m<16; m<<=1) pj += __shfl_xor(pj, m);
      if (lm == 0) scred[w][mt*16 + lk*4 + j] = pj;
    }
  }
  __syncthreads();
  if (tid < 64){
    float s = scred[0][tid]+scred[1][tid]+scred[2][tid]+scred[3][tid] + ba2[0];
    scores[(size_t)(bb+tid)*TT + t] = s;
  }
}

// ================= softmax over T + context =================
__global__ __launch_bounds__(256,2) void ctx_kernel(
    const uint16_t* __restrict__ h1, const float* __restrict__ scores,
    float* __restrict__ context, int BR)
{
  const int b = blockIdx.x, tid = threadIdx.x;
  __shared__ float at[TT];
  __shared__ float red[8];
  float sc = scores[(size_t)b*TT + tid];
  float m = sc;
  #pragma unroll
  for (int d=1; d<64; d<<=1) m = fmaxf(m, __shfl_xor(m, d));
  if ((tid&63)==0) red[tid>>6] = m;
  __syncthreads();
  m = fmaxf(fmaxf(red[0],red[1]), fmaxf(red[2],red[3]));
  float e = __expf(sc - m);
  float s = e;
  #pragma unroll
  for (int d=1; d<64; d<<=1) s += __shfl_xor(s, d);
  if ((tid&63)==0) red[4+(tid>>6)] = s;
  __syncthreads();
  s = red[4]+red[5]+red[6]+red[7];
  at[tid] = e * rcpf(s);
  __syncthreads();

  float acc = 0.f;
  const uint16_t* hp = h1 + (size_t)b*256 + tid;
  #pragma unroll 8
  for (int t2=0; t2<TT; ++t2) acc += at[t2] * bf2f(hp[(size_t)t2*BR*256]);
  context[(size_t)b*256 + tid] = acc;
}

// ================= head =================
__global__ __launch_bounds__(128,2) void head_kernel(
    const float* __restrict__ ctx, const float* __restrict__ Wf1,
    const float* __restrict__ bf1, const float* __restrict__ g2,
    const float* __restrict__ b2, const float* __restrict__ Wf2,
    const float* __restrict__ bf2v, float* __restrict__ out, int b_off)
{
  const int b = blockIdx.x, tid = threadIdx.x;
  __shared__ float cx[256];
  __shared__ float zb[128];
  __shared__ float red[4];
  cx[tid]       = ctx[(size_t)b*256 + tid];
  cx[128+tid]   = ctx[(size_t)b*256 + 128 + tid];
  __syncthreads();
  float y = bf1[tid];
  const float* wr = Wf1 + (size_t)tid*256;
  #pragma unroll 8
  for (int k=0; k<256; ++k) y += cx[k]*wr[k];
  float s = y;
  #pragma unroll
  for (int d=1; d<64; d<<=1) s += __shfl_xor(s, d);
  if ((tid&63)==0) red[tid>>6] = s;
  __syncthreads();
  float mu = (red[0]+red[1])*(1.f/128.f);
  float dv = y - mu;
  float q = dv*dv;
  #pragma unroll
  for (int d=1; d<64; d<<=1) q += __shfl_xor(q, d);
  if ((tid&63)==0) red[2+(tid>>6)] = q;
  __syncthreads();
  float var = (red[2]+red[3])*(1.f/128.f);
  float z = dv*rsqrtf(var + 1e-5f)*g2[tid] + b2[tid];
  z = fmaxf(z, 0.f);
  zb[tid] = z;
  __syncthreads();
  if (tid < 5){
    float o = bf2v[tid];
    const float* wp = Wf2 + (size_t)tid*128;
    for (int k=0; k<128; ++k) o += zb[k]*wp[k];
    out[(size_t)(b_off + b)*5 + tid] = o;
  }
}

extern "C" void kernel_launch(void* const* d_in, const int* in_sizes, int n_in,
                              void* d_out, int out_size, void* d_ws, size_t ws_size,
                              hipStream_t stream)
{
  const float* x    = (const float*)d_in[0];
  const float* ln_g = (const float*)d_in[1];
  const float* ln_b = (const float*)d_in[2];
  const float* Wih0 = (const float*)d_in[3];
  const float* Whh0 = (const float*)d_in[4];
  const float* bih0 = (const float*)d_in[5];
  const float* bhh0 = (const float*)d_in[6];
  const float* Wih1 = (const float*)d_in[7];
  const float* Whh1 = (const float*)d_in[8];
  const float* bih1 = (const float*)d_in[9];
  const float* bhh1 = (const float*)d_in[10];
  const float* Wa1  = (const float*)d_in[11];
  const float* ba1  = (const float*)d_in[12];
  const float* Wa2  = (const float*)d_in[13];
  const float* ba2  = (const float*)d_in[14];
  const float* Wf1  = (const float*)d_in[15];
  const float* bf1  = (const float*)d_in[16];
  const float* ln2g = (const float*)d_in[17];
  const float* ln2b = (const float*)d_in[18];
  const float* Wf2  = (const float*)d_in[19];
  const float* bf2  = (const float*)d_in[20];
  float* out = (float*)d_out;

  char* wsb = (char*)d_ws;
  const size_t HBf = (size_t)TT*1024*256*2;   // 134,217,728

  prep_wih1<<<128, 256, 0, stream>>>(Wih1);

  if (ws_size >= 2*HBf){
    // ---------- FULL: whole batch in one pass; scores/ctx alias dead h0 ----------
    uint16_t* h0 = (uint16_t*)wsb;
    uint16_t* h1 = (uint16_t*)(wsb + HBf);
    float* scoresP = (float*)wsb;
    float* ctxP    = (float*)(wsb + (size_t)1024*TT*4);

    lstm0_kernel<<<512, 512, 0, stream>>>(x, ln_g, ln_b, Wih0, Whh0, bih0, bhh0,
                                          h0, 256, 1024, 0);
    lstm1_kernel<<<512, 512, 0, stream>>>(h0, Whh1, bih1, bhh1, h1, 256, 1024);
    scores_kernel<<<TT*16, 256, 0, stream>>>(h1, Wa1, ba1, Wa2, ba2, scoresP, 16, 1024);
    ctx_kernel   <<<1024, 256, 0, stream>>>(h1, scoresP, ctxP, 1024);
    head_kernel  <<<1024, 128, 0, stream>>>(ctxP, Wf1, bf1, ln2g, ln2b, Wf2, bf2, out, 0);
  } else {
    // ---------- fallback: rounds of BR samples ----------
    int BR = 512;
    while (BR > 64){
      size_t HB = (size_t)TT*BR*256*2;
      if (2*HB + 2*((size_t)BR*256*4) <= ws_size) break;
      BR >>= 1;
    }
    const size_t HB = (size_t)TT*BR*256*2;
    uint16_t* h0 = (uint16_t*)wsb;
    uint16_t* h1 = (uint16_t*)(wsb + HB);
    float* scoresP = (float*)(wsb + 2*HB);
    float* ctxP    = (float*)(wsb + 2*HB + (size_t)BR*256*4);
    const int nb = BR/NS;

    for (int b_off = 0; b_off < 1024; b_off += BR){
      lstm0_kernel<<<2*nb, 512, 0, stream>>>(x, ln_g, ln_b, Wih0, Whh0, bih0, bhh0,
                                             h0, nb, BR, b_off);
      lstm1_kernel<<<2*nb, 512, 0, stream>>>(h0, Whh1, bih1, bhh1, h1, nb, BR);
      scores_kernel<<<TT*(BR/64), 256, 0, stream>>>(h1, Wa1, ba1, Wa2, ba2, scoresP,
                                                    BR/64, BR);
      ctx_kernel   <<<BR, 256, 0, stream>>>(h1, scoresP, ctxP, BR);
      head_kernel  <<<BR, 128, 0, stream>>>(ctxP, Wf1, bf1, ln2g, ln2b, Wf2, bf2,
                                            out, b_off);
    }
  }
}

// Round 11
// 755.782 us; speedup vs baseline: 1.6038x; 1.6038x over previous
//
#include <hip/hip_runtime.h>
#include <stdint.h>

#define TT 256
#define NS 8
#define CH 8

typedef __attribute__((ext_vector_type(4))) float f32x4;
typedef __attribute__((ext_vector_type(8))) short s16x8;
typedef __attribute__((ext_vector_type(2))) unsigned int u32x2;

#define DEV static __device__ __forceinline__

// prepped bf16 Wih1 fragments: [dir][ntg(32)][kt(8)][lane(64)][8]
__device__ uint16_t g_W1f[2*32*8*64*8];

DEV short f2bf(float f){
  union{float f; uint32_t u;} v; v.f = f;
  uint32_t r = v.u + 0x7fffu + ((v.u>>16)&1u);
  return (short)(r>>16);
}
DEV float bf2f(uint32_t u16){
  union{uint32_t u; float f;} v; v.u = u16<<16; return v.f;
}
DEV uint32_t pk2(float a, float b){
  return (uint32_t)(uint16_t)f2bf(a) | ((uint32_t)(uint16_t)f2bf(b)<<16);
}
DEV float rcpf(float x){ return __builtin_amdgcn_rcpf(x); }
DEV float sigm(float x){ return rcpf(1.f + __expf(-x)); }
DEV float tanh_f(float x){ float e = __expf(2.f*x); return 1.f - 2.f*rcpf(e+1.f); }
DEV f32x4 MFMA(s16x8 a, s16x8 b, f32x4 c){
  return __builtin_amdgcn_mfma_f32_16x16x32_bf16(a, b, c, 0, 0, 0);
}
DEV s16x8 cvt8(const float* p){
  f32x4 a = *(const f32x4*)p;
  f32x4 b = *(const f32x4*)(p+4);
  s16x8 o;
  o[0]=f2bf(a[0]); o[1]=f2bf(a[1]); o[2]=f2bf(a[2]); o[3]=f2bf(a[3]);
  o[4]=f2bf(b[0]); o[5]=f2bf(b[1]); o[6]=f2bf(b[2]); o[7]=f2bf(b[3]);
  return o;
}
// barrier that drains LDS only (global stores/loads stay in flight)
DEV void bar_lds(){
  asm volatile("s_waitcnt lgkmcnt(0)" ::: "memory");
  __builtin_amdgcn_s_barrier();
}

// flush one step's h (8 rows x 128 cols bf16) straight from a 4KB hbuf frame.
DEV void flush_step(const short* hb, uint16_t* __restrict__ hdst, int tp,
                    int dir, int BR, int bg, int tid){
  if (tid < 128){
    int row = tid >> 4, part = tid & 15;
    int tg = dir ? (TT-1-tp) : tp;
    s16x8 v = *(const s16x8*)((const char*)hb + row*256 + (((part ^ row)&15)<<4));
    *(s16x8*)(hdst + ((size_t)tg*BR + bg*NS + row)*256 + dir*128 + part*8) = v;
  }
}

// ---------------- Wih1 -> bf16 B-fragment layout ----------------
__global__ __launch_bounds__(256) void prep_wih1(const float* __restrict__ Wih1)
{
  int tid = blockIdx.x*256 + threadIdx.x;   // 32768 total
  int l = tid & 63, kt = (tid>>6)&7, ntg = (tid>>9)&31, dir = (tid>>14)&1;
  int lm = l&15, lk = l>>4;
  int n = ntg*16 + lm;
  s16x8 o = cvt8(Wih1 + ((size_t)(dir*512 + n))*256 + kt*32 + lk*8);
  *(s16x8*)(&g_W1f[(size_t)tid*8]) = o;
}

// ================= BiLSTM layer 0 (LN fused; 6 -> 128/dir), NS=8 =================
__global__ __launch_bounds__(512,2) void lstm0_kernel(
    const float* __restrict__ x, const float* __restrict__ lng,
    const float* __restrict__ lnb,
    const float* __restrict__ Wih0, const float* __restrict__ Whh0,
    const float* __restrict__ bih0, const float* __restrict__ bhh0,
    uint16_t* __restrict__ h0, int nb, int BR, int b_off)
{
  const int dir = blockIdx.x / nb, bg = blockIdx.x % nb;
  const int tid = threadIdx.x, w = tid>>6, l = tid&63;
  const int lm = l&15, lk = l>>4;
  const int gb = b_off + bg*NS;

  __shared__ short hbuf[2][2048];     // 8 KB, XOR(row<<4) swizzle
  __shared__ short xnbf[TT*NS*8];     // 32 KB
  __shared__ short bxs[8*4*64*8];     // 32 KB

  for (int i=tid; i<4096; i+=512) ((short*)hbuf)[i] = 0;

  #pragma unroll
  for (int it=0; it<4; ++it){
    int pr = it*512 + tid;
    int r = pr >> 8, t = pr & 255;
    const float* px = x + ((size_t)(gb+r)*TT + t)*6;
    float v[6]; float mu=0.f, var=0.f;
    #pragma unroll
    for (int d=0; d<6; ++d){ v[d]=px[d]; mu+=v[d]; }
    mu *= (1.f/6.f);
    #pragma unroll
    for (int d=0; d<6; ++d){ float dd=v[d]-mu; var+=dd*dd; }
    float rs = rsqrtf(var*(1.f/6.f) + 1e-5f);
    s16x8 vv;
    #pragma unroll
    for (int d=0; d<6; ++d) vv[d] = f2bf((v[d]-mu)*rs*lng[d] + lnb[d]);
    vv[6]=0; vv[7]=0;
    *(s16x8*)&xnbf[(t*NS + r)*8] = vv;
  }

  const int c = w*16 + lm;
  s16x8 bw[4][4];
  float biasc[4];
  #pragma unroll
  for (int G=0; G<4; ++G){
    const int n = G*128 + c;
    biasc[G] = bih0[dir*512+n] + bhh0[dir*512+n];
    #pragma unroll
    for (int kt=0; kt<4; ++kt)
      bw[G][kt] = cvt8(Whh0 + ((size_t)(dir*512+n))*128 + kt*32 + lk*8);
    s16x8 tx;
    #pragma unroll
    for (int j=0; j<8; ++j){
      int k = lk*8 + j;
      tx[j] = (k<6) ? f2bf(Wih0[(size_t)(dir*512+n)*6 + k]) : (short)0;
    }
    *(s16x8*)&bxs[((w*4+G)*64 + l)*8] = tx;
  }

  const int r0 = ((l>>4)&1)*4 + ((l<32)?0:2);
  float cst[2] = {0.f, 0.f};
  __syncthreads();

  for (int t=0; t<TT; ++t){
    const int tt = dir ? (TT-1-t) : t;
    const int rd = t & 1;
    s16x8 ah[4];
    #pragma unroll
    for (int kt=0; kt<4; ++kt){
      int off = rd*4096 + lm*256 + ((kt*64 + lk*16) ^ (lm<<4));
      ah[kt] = *(const s16x8*)((const char*)hbuf + off);
    }
    s16x8 ax = {0,0,0,0,0,0,0,0};
    if (l < 8) ax = *(const s16x8*)&xnbf[(tt*NS + l)*8];

    f32x4 acc[4];
    #pragma unroll
    for (int G=0; G<4; ++G){
      f32x4 a = {0.f,0.f,0.f,0.f};
      #pragma unroll
      for (int kt=0; kt<4; ++kt) a = MFMA(ah[kt], bw[G][kt], a);
      s16x8 bx = *(const s16x8*)&bxs[((w*4+G)*64 + l)*8];
      a = MFMA(ax, bx, a);
      acc[G] = a;
    }

    float g0[4], g1[4];
    #pragma unroll
    for (int G=0; G<4; ++G){
      float o2 = __shfl(acc[G][2], l & 31);
      float o3 = __shfl(acc[G][3], l & 31);
      g0[G] = ((l<32) ? acc[G][0] : o2) + biasc[G];
      g1[G] = ((l<32) ? acc[G][1] : o3) + biasc[G];
    }
    float hv[2];
    {
      float cc = sigm(g0[1])*cst[0] + sigm(g0[0])*tanh_f(g0[2]);
      cst[0] = cc; hv[0] = sigm(g0[3])*tanh_f(cc);
      cc = sigm(g1[1])*cst[1] + sigm(g1[0])*tanh_f(g1[2]);
      cst[1] = cc; hv[1] = sigm(g1[3])*tanh_f(cc);
    }

    #pragma unroll
    for (int q=0; q<2; ++q){
      int r = r0 + q;
      *(short*)((char*)hbuf + (rd^1)*4096 + r*256 + ((c*2) ^ (r<<4))) = f2bf(hv[q]);
    }
    if (t > 0)
      flush_step(hbuf[rd], h0, t-1, dir, BR, bg, tid);
    bar_lds();
  }
  flush_step(hbuf[0], h0, TT-1, dir, BR, bg, tid);
}

// ============ lstm1 SAFE: round-9 version (xp via LDS xpbuf) ============
__global__ __launch_bounds__(512,2) void lstm1_safe(
    const uint16_t* __restrict__ h0,
    const float* __restrict__ Whh1, const float* __restrict__ bih1,
    const float* __restrict__ bhh1, uint16_t* __restrict__ h1,
    int nb, int BR)
{
  const int dir = blockIdx.x / nb, bg = blockIdx.x % nb;
  const int tid = threadIdx.x, w = tid>>6, l = tid&63;
  const int lm = l&15, lk = l>>4;

  __shared__ short hbuf[2][2048];
  __shared__ short abuf[2][16384];
  __shared__ u32x2 xpbuf[8192];

  for (int i=tid; i<4096; i+=512) ((short*)hbuf)[i] = 0;

  const int c = w*16 + lm;
  s16x8 bw[4][4];
  float biasv[4];
  #pragma unroll
  for (int G=0; G<4; ++G){
    const int n = G*128 + c;
    biasv[G] = bih1[dir*512+n] + bhh1[dir*512+n];
    #pragma unroll
    for (int kt=0; kt<4; ++kt)
      bw[G][kt] = cvt8(Whh1 + ((size_t)(dir*512+n))*128 + kt*32 + lk*8);
  }

  const int r0 = ((l>>4)&1)*4 + ((l<32)?0:2);
  float cst[2] = {0.f,0.f};
  s16x8 vst[4];

  #pragma unroll
  for (int it=0; it<4; ++it){
    int sid = it*512 + tid, row = sid>>5, sl = sid&31, s = row>>3, b = row&7;
    int tg = dir ? (TT-1-s) : s;
    vst[it] = *(const s16x8*)(h0 + ((size_t)tg*BR + bg*NS + b)*256 + sl*8);
  }
  #pragma unroll
  for (int it=0; it<4; ++it){
    int sid = it*512 + tid, row = sid>>5, sl = sid&31;
    *(s16x8*)((char*)abuf + row*512 + ((sl ^ (row&15))<<4)) = vst[it];
  }
  __syncthreads();

  for (int ch=0; ch<TT/CH; ++ch){
    const int cur = ch & 1;
    const char* ab = (const char*)abuf + cur*32768;

    if (ch < TT/CH-1){
      #pragma unroll
      for (int it=0; it<4; ++it){
        int sid = it*512 + tid, row = sid>>5, sl = sid&31, s = row>>3, b = row&7;
        int ts = (ch+1)*CH + s;
        int tg = dir ? (TT-1-ts) : ts;
        vst[it] = *(const s16x8*)(h0 + ((size_t)tg*BR + bg*NS + b)*256 + sl*8);
      }
    }

    #pragma unroll
    for (int G=0; G<4; ++G){
      f32x4 acc[4];
      #pragma unroll
      for (int mt=0; mt<4; ++mt) acc[mt] = (f32x4){biasv[G],biasv[G],biasv[G],biasv[G]};
      #pragma unroll
      for (int kt=0; kt<8; ++kt){
        s16x8 bfr = *(const s16x8*)(&g_W1f[(((size_t)(dir*32 + G*8 + w)*8 + kt)*64 + l)*8]);
        #pragma unroll
        for (int mt=0; mt<4; ++mt){
          int row = mt*16 + lm;
          s16x8 afr = *(const s16x8*)(ab + row*512 + (((kt*4+lk) ^ (row&15))<<4));
          acc[mt] = MFMA(afr, bfr, acc[mt]);
        }
      }
      #pragma unroll
      for (int mt=0; mt<4; ++mt){
        u32x2 pw;
        pw[0] = pk2(acc[mt][0], acc[mt][1]);
        pw[1] = pk2(acc[mt][2], acc[mt][3]);
        xpbuf[((w*4+G)*4+mt)*64 + l] = pw;
      }
    }

    if (ch < TT/CH-1){
      char* ab2 = (char*)abuf + (cur^1)*32768;
      #pragma unroll
      for (int it=0; it<4; ++it){
        int sid = it*512 + tid, row = sid>>5, sl = sid&31;
        *(s16x8*)(ab2 + row*512 + ((sl ^ (row&15))<<4)) = vst[it];
      }
    }
    bar_lds();

    #pragma unroll
    for (int s=0; s<CH; ++s){
      const int gs = ch*CH + s;
      const int rd = gs & 1;
      const int lane2 = ((((s&1)<<1) + lk)<<4) + lm;

      f32x4 acc4[4];
      #pragma unroll
      for (int G=0; G<4; ++G){
        u32x2 pw = xpbuf[((w*4+G)*4 + (s>>1))*64 + lane2];
        acc4[G] = (f32x4){bf2f(pw[0]&0xffffu), bf2f(pw[0]>>16),
                          bf2f(pw[1]&0xffffu), bf2f(pw[1]>>16)};
      }

      s16x8 ah[4];
      #pragma unroll
      for (int kt=0; kt<4; ++kt){
        int off = rd*4096 + lm*256 + ((kt*64 + lk*16) ^ (lm<<4));
        ah[kt] = *(const s16x8*)((const char*)hbuf + off);
      }
      #pragma unroll
      for (int G=0; G<4; ++G){
        #pragma unroll
        for (int kt=0; kt<4; ++kt)
          acc4[G] = MFMA(ah[kt], bw[G][kt], acc4[G]);
      }

      float g0[4], g1[4];
      #pragma unroll
      for (int G=0; G<4; ++G){
        float o2 = __shfl(acc4[G][2], l & 31);
        float o3 = __shfl(acc4[G][3], l & 31);
        g0[G] = (l<32) ? acc4[G][0] : o2;
        g1[G] = (l<32) ? acc4[G][1] : o3;
      }
      float hv[2];
      float cc = sigm(g0[1])*cst[0] + sigm(g0[0])*tanh_f(g0[2]);
      cst[0] = cc; hv[0] = sigm(g0[3])*tanh_f(cc);
      cc = sigm(g1[1])*cst[1] + sigm(g1[0])*tanh_f(g1[2]);
      cst[1] = cc; hv[1] = sigm(g1[3])*tanh_f(cc);

      #pragma unroll
      for (int q=0; q<2; ++q){
        int r = r0 + q;
        *(short*)((char*)hbuf + (rd^1)*4096 + r*256 + ((c*2) ^ (r<<4))) = f2bf(hv[q]);
      }
      if (gs > 0)
        flush_step(hbuf[rd], h1, gs-1, dir, BR, bg, tid);
      bar_lds();
    }
  }
  flush_step(hbuf[0], h1, TT-1, dir, BR, bg, tid);
}

// ============ lstm1 AGG: xp in registers, phase A interleaved into phase B ============
__global__ __launch_bounds__(512) void lstm1_agg(
    const uint16_t* __restrict__ h0,
    const float* __restrict__ Whh1, const float* __restrict__ bih1,
    const float* __restrict__ bhh1, uint16_t* __restrict__ h1,
    int nb, int BR)
{
  const int dir = blockIdx.x / nb, bg = blockIdx.x % nb;
  const int tid = threadIdx.x, w = tid>>6, l = tid&63;
  const int lm = l&15, lk = l>>4;

  __shared__ short hbuf[2][2048];     // 8 KB
  __shared__ short abuf[2][16384];    // 64 KB

  for (int i=tid; i<4096; i+=512) ((short*)hbuf)[i] = 0;

  const int col = w*16 + lm;
  s16x8 bw[4][4];
  float biasv[4];
  #pragma unroll
  for (int G=0; G<4; ++G){
    const int n = G*128 + col;
    biasv[G] = bih1[dir*512+n] + bhh1[dir*512+n];
    #pragma unroll
    for (int kt=0; kt<4; ++kt)
      bw[G][kt] = cvt8(Whh1 + ((size_t)(dir*512+n))*128 + kt*32 + lk*8);
  }

  const int r0 = ((l>>4)&1)*4 + ((l<32)?0:2);
  float cst[2] = {0.f,0.f};
  uint32_t xpc[4][4][2], xpn[4][4][2];
  s16x8 vst[4];
  f32x4 accA[4];

  // ---- prologue: chunk 0 -> abuf[0]; phase A(0) -> xpc; chunk 1 -> abuf[1] ----
  #pragma unroll
  for (int it=0; it<4; ++it){
    int sid = it*512 + tid, row = sid>>5, sl = sid&31, s = row>>3, b = row&7;
    int tg = dir ? (TT-1-s) : s;
    vst[it] = *(const s16x8*)(h0 + ((size_t)tg*BR + bg*NS + b)*256 + sl*8);
  }
  #pragma unroll
  for (int it=0; it<4; ++it){
    int sid = it*512 + tid, row = sid>>5, sl = sid&31;
    *(s16x8*)((char*)abuf + row*512 + ((sl ^ (row&15))<<4)) = vst[it];
  }
  __syncthreads();

  #pragma unroll
  for (int G=0; G<4; ++G){
    f32x4 acc[4];
    #pragma unroll
    for (int mt=0; mt<4; ++mt) acc[mt] = (f32x4){biasv[G],biasv[G],biasv[G],biasv[G]};
    #pragma unroll
    for (int kt=0; kt<8; ++kt){
      s16x8 bfr = *(const s16x8*)(&g_W1f[(((size_t)(dir*32 + G*8 + w)*8 + kt)*64 + l)*8]);
      #pragma unroll
      for (int mt=0; mt<4; ++mt){
        int row = mt*16 + lm;
        s16x8 afr = *(const s16x8*)((const char*)abuf + row*512 + (((kt*4+lk) ^ (row&15))<<4));
        acc[mt] = MFMA(afr, bfr, acc[mt]);
      }
    }
    #pragma unroll
    for (int mt=0; mt<4; ++mt){
      xpc[G][mt][0] = pk2(acc[mt][0], acc[mt][1]);
      xpc[G][mt][1] = pk2(acc[mt][2], acc[mt][3]);
    }
  }

  #pragma unroll
  for (int it=0; it<4; ++it){
    int sid = it*512 + tid, row = sid>>5, sl = sid&31, s = row>>3, b = row&7;
    int tg = dir ? (TT-1-(CH+s)) : (CH+s);
    vst[it] = *(const s16x8*)(h0 + ((size_t)tg*BR + bg*NS + b)*256 + sl*8);
  }
  #pragma unroll
  for (int it=0; it<4; ++it){
    int sid = it*512 + tid, row = sid>>5, sl = sid&31;
    *(s16x8*)((char*)abuf + 32768 + row*512 + ((sl ^ (row&15))<<4)) = vst[it];
  }
  __syncthreads();

  // ---- main loop: phase B(ck) with interleaved phase A(ck+1) ----
  for (int ck=0; ck<TT/CH; ++ck){
    const char* abn = (const char*)abuf + ((ck+1)&1)*32768;  // A-source for chunk ck+1
    char* abw = (char*)abuf + (ck&1)*32768;                  // stage target for chunk ck+2

    if (ck < TT/CH-2){
      #pragma unroll
      for (int it=0; it<4; ++it){
        int sid = it*512 + tid, row = sid>>5, sl = sid&31, s = row>>3, b = row&7;
        int ts = (ck+2)*CH + s;
        int tg = dir ? (TT-1-ts) : ts;
        vst[it] = *(const s16x8*)(h0 + ((size_t)tg*BR + bg*NS + b)*256 + sl*8);
      }
    }

    #pragma unroll
    for (int s=0; s<CH; ++s){
      const int gs = ck*CH + s;
      const int rd = gs & 1;
      const int src = ((((s&1)<<1) + lk)*16 + lm) & 63;

      f32x4 acc4[4];
      #pragma unroll
      for (int G=0; G<4; ++G){
        uint32_t p0 = (uint32_t)__shfl((int)xpc[G][s>>1][0], src);
        uint32_t p1 = (uint32_t)__shfl((int)xpc[G][s>>1][1], src);
        acc4[G] = (f32x4){bf2f(p0&0xffffu), bf2f(p0>>16), bf2f(p1&0xffffu), bf2f(p1>>16)};
      }

      s16x8 ah[4];
      #pragma unroll
      for (int kt=0; kt<4; ++kt){
        int off = rd*4096 + lm*256 + ((kt*64 + lk*16) ^ (lm<<4));
        ah[kt] = *(const s16x8*)((const char*)hbuf + off);
      }
      #pragma unroll
      for (int G=0; G<4; ++G){
        #pragma unroll
        for (int kt=0; kt<4; ++kt)
          acc4[G] = MFMA(ah[kt], bw[G][kt], acc4[G]);
      }

      // interleaved phase A for chunk ck+1: G-pass s>>1, kt half (s&1)
      if (ck < TT/CH-1){
        const int G2 = s>>1;
        if ((s&1) == 0){
          #pragma unroll
          for (int mt=0; mt<4; ++mt) accA[mt] = (f32x4){biasv[G2],biasv[G2],biasv[G2],biasv[G2]};
        }
        #pragma unroll
        for (int kq=0; kq<4; ++kq){
          const int kt = (s&1)*4 + kq;
          s16x8 bfr = *(const s16x8*)(&g_W1f[(((size_t)(dir*32 + G2*8 + w)*8 + kt)*64 + l)*8]);
          #pragma unroll
          for (int mt=0; mt<4; ++mt){
            int row = mt*16 + lm;
            s16x8 afr = *(const s16x8*)(abn + row*512 + (((kt*4+lk) ^ (row&15))<<4));
            accA[mt] = MFMA(afr, bfr, accA[mt]);
          }
        }
        if (s & 1){
          #pragma unroll
          for (int mt=0; mt<4; ++mt){
            xpn[G2][mt][0] = pk2(accA[mt][0], accA[mt][1]);
            xpn[G2][mt][1] = pk2(accA[mt][2], accA[mt][3]);
          }
        }
      }

      float g0[4], g1[4];
      #pragma unroll
      for (int G=0; G<4; ++G){
        float o2 = __shfl(acc4[G][2], l & 31);
        float o3 = __shfl(acc4[G][3], l & 31);
        g0[G] = (l<32) ? acc4[G][0] : o2;
        g1[G] = (l<32) ? acc4[G][1] : o3;
      }
      float hv[2];
      float cc = sigm(g0[1])*cst[0] + sigm(g0[0])*tanh_f(g0[2]);
      cst[0] = cc; hv[0] = sigm(g0[3])*tanh_f(cc);
      cc = sigm(g1[1])*cst[1] + sigm(g1[0])*tanh_f(g1[2]);
      cst[1] = cc; hv[1] = sigm(g1[3])*tanh_f(cc);

      #pragma unroll
      for (int q=0; q<2; ++q){
        int r = r0 + q;
        *(short*)((char*)hbuf + (rd^1)*4096 + r*256 + ((col*2) ^ (r<<4))) = f2bf(hv[q]);
      }

      // stage chunk ck+2 into the free abuf half (visible after this barrier)
      if (s == 7 && ck < TT/CH-2){
        #pragma unroll
        for (int it=0; it<4; ++it){
          int sid = it*512 + tid, row = sid>>5, sl = sid&31;
          *(s16x8*)(abw + row*512 + ((sl ^ (row&15))<<4)) = vst[it];
        }
      }

      if (gs > 0)
        flush_step(hbuf[rd], h1, gs-1, dir, BR, bg, tid);
      bar_lds();
    }

    if (ck < TT/CH-1){
      #pragma unroll
      for (int G=0; G<4; ++G)
        #pragma unroll
        for (int mt=0; mt<4; ++mt){
          xpc[G][mt][0] = xpn[G][mt][0];
          xpc[G][mt][1] = xpn[G][mt][1];
        }
    }
  }
  flush_step(hbuf[0], h1, TT-1, dir, BR, bg, tid);
}

// ================= attention scores =================
__global__ __launch_bounds__(256,2) void scores_kernel(
    const uint16_t* __restrict__ h1, const float* __restrict__ Wa1,
    const float* __restrict__ ba1, const float* __restrict__ Wa2,
    const float* __restrict__ ba2, float* __restrict__ scores,
    int nbb, int BR)
{
  const int bx = blockIdx.x;
  const int t = bx / nbb, bb = (bx - t*nbb) * 64;
  const int tid = threadIdx.x, w = tid>>6, l = tid&63;
  const int lm = l&15, lk = l>>4;
  __shared__ short abuf[64*256];
  __shared__ float scred[4][64];

  #pragma unroll
  for (int it=0; it<8; ++it){
    int sid = it*256 + tid, row = sid>>5, sl = sid&31;
    s16x8 v = *(const s16x8*)(h1 + ((size_t)t*BR + bb + row)*256 + sl*8);
    *(s16x8*)((char*)abuf + row*512 + ((sl ^ (row&15))<<4)) = v;
  }

  s16x8 bwa[2][8]; float b1v[2], wa2v[2];
  #pragma unroll
  for (int nt=0; nt<2; ++nt){
    int n = w*32 + nt*16 + lm;
    b1v[nt] = ba1[n]; wa2v[nt] = Wa2[n];
    #pragma unroll
    for (int kt=0; kt<8; ++kt)
      bwa[nt][kt] = cvt8(Wa1 + (size_t)n*256 + kt*32 + lk*8);
  }
  __syncthreads();

  #pragma unroll
  for (int mt=0; mt<4; ++mt){
    f32x4 a0 = {b1v[0],b1v[0],b1v[0],b1v[0]};
    f32x4 a1 = {b1v[1],b1v[1],b1v[1],b1v[1]};
    #pragma unroll
    for (int kt=0; kt<8; ++kt){
      int row = mt*16 + lm;
      s16x8 af = *(const s16x8*)((const char*)abuf + row*512 + (((kt*4+lk) ^ (row&15))<<4));
      a0 = MFMA(af, bwa[0][kt], a0);
      a1 = MFMA(af, bwa[1][kt], a1);
    }
    #pragma unroll
    for (int j=0; j<4; ++j){
      float pj = tanh_f(a0[j])*wa2v[0] + tanh_f(a1[j])*wa2v[1];
      #pragma unroll
      for (int m=1; m<16; m<<=1) pj += __shfl_xor(pj, m);
      if (lm == 0) scred[w][mt*16 + lk*4 + j] = pj;
    }
  }
  __syncthreads();
  if (tid < 64){
    float s = scred[0][tid]+scred[1][tid]+scred[2][tid]+scred[3][tid] + ba2[0];
    scores[(size_t)(bb+tid)*TT + t] = s;
  }
}

// ================= softmax over T + context =================
__global__ __launch_bounds__(256,2) void ctx_kernel(
    const uint16_t* __restrict__ h1, const float* __restrict__ scores,
    float* __restrict__ context, int BR)
{
  const int b = blockIdx.x, tid = threadIdx.x;
  __shared__ float at[TT];
  __shared__ float red[8];
  float sc = scores[(size_t)b*TT + tid];
  float m = sc;
  #pragma unroll
  for (int d=1; d<64; d<<=1) m = fmaxf(m, __shfl_xor(m, d));
  if ((tid&63)==0) red[tid>>6] = m;
  __syncthreads();
  m = fmaxf(fmaxf(red[0],red[1]), fmaxf(red[2],red[3]));
  float e = __expf(sc - m);
  float s = e;
  #pragma unroll
  for (int d=1; d<64; d<<=1) s += __shfl_xor(s, d);
  if ((tid&63)==0) red[4+(tid>>6)] = s;
  __syncthreads();
  s = red[4]+red[5]+red[6]+red[7];
  at[tid] = e * rcpf(s);
  __syncthreads();

  float acc = 0.f;
  const uint16_t* hp = h1 + (size_t)b*256 + tid;
  #pragma unroll 8
  for (int t2=0; t2<TT; ++t2) acc += at[t2] * bf2f(hp[(size_t)t2*BR*256]);
  context[(size_t)b*256 + tid] = acc;
}

// ================= head =================
__global__ __launch_bounds__(128,2) void head_kernel(
    const float* __restrict__ ctx, const float* __restrict__ Wf1,
    const float* __restrict__ bf1, const float* __restrict__ g2,
    const float* __restrict__ b2, const float* __restrict__ Wf2,
    const float* __restrict__ bf2v, float* __restrict__ out, int b_off)
{
  const int b = blockIdx.x, tid = threadIdx.x;
  __shared__ float cx[256];
  __shared__ float zb[128];
  __shared__ float red[4];
  cx[tid]       = ctx[(size_t)b*256 + tid];
  cx[128+tid]   = ctx[(size_t)b*256 + 128 + tid];
  __syncthreads();
  float y = bf1[tid];
  const float* wr = Wf1 + (size_t)tid*256;
  #pragma unroll 8
  for (int k=0; k<256; ++k) y += cx[k]*wr[k];
  float s = y;
  #pragma unroll
  for (int d=1; d<64; d<<=1) s += __shfl_xor(s, d);
  if ((tid&63)==0) red[tid>>6] = s;
  __syncthreads();
  float mu = (red[0]+red[1])*(1.f/128.f);
  float dv = y - mu;
  float q = dv*dv;
  #pragma unroll
  for (int d=1; d<64; d<<=1) q += __shfl_xor(q, d);
  if ((tid&63)==0) red[2+(tid>>6)] = q;
  __syncthreads();
  float var = (red[2]+red[3])*(1.f/128.f);
  float z = dv*rsqrtf(var + 1e-5f)*g2[tid] + b2[tid];
  z = fmaxf(z, 0.f);
  zb[tid] = z;
  __syncthreads();
  if (tid < 5){
    float o = bf2v[tid];
    const float* wp = Wf2 + (size_t)tid*128;
    for (int k=0; k<128; ++k) o += zb[k]*wp[k];
    out[(size_t)(b_off + b)*5 + tid] = o;
  }
}

extern "C" void kernel_launch(void* const* d_in, const int* in_sizes, int n_in,
                              void* d_out, int out_size, void* d_ws, size_t ws_size,
                              hipStream_t stream)
{
  const float* x    = (const float*)d_in[0];
  const float* ln_g = (const float*)d_in[1];
  const float* ln_b = (const float*)d_in[2];
  const float* Wih0 = (const float*)d_in[3];
  const float* Whh0 = (const float*)d_in[4];
  const float* bih0 = (const float*)d_in[5];
  const float* bhh0 = (const float*)d_in[6];
  const float* Wih1 = (const float*)d_in[7];
  const float* Whh1 = (const float*)d_in[8];
  const float* bih1 = (const float*)d_in[9];
  const float* bhh1 = (const float*)d_in[10];
  const float* Wa1  = (const float*)d_in[11];
  const float* ba1  = (const float*)d_in[12];
  const float* Wa2  = (const float*)d_in[13];
  const float* ba2  = (const float*)d_in[14];
  const float* Wf1  = (const float*)d_in[15];
  const float* bf1  = (const float*)d_in[16];
  const float* ln2g = (const float*)d_in[17];
  const float* ln2b = (const float*)d_in[18];
  const float* Wf2  = (const float*)d_in[19];
  const float* bf2  = (const float*)d_in[20];
  float* out = (float*)d_out;

  // choose lstm1 variant: AGG only if it compiled spill-free (deterministic)
  bool useAgg = false;
  {
    hipFuncAttributes fa;
    if (hipFuncGetAttributes(&fa, (const void*)lstm1_agg) == hipSuccess &&
        fa.localSizeBytes == 0)
      useAgg = true;
  }

  char* wsb = (char*)d_ws;
  const size_t HBf = (size_t)TT*1024*256*2;   // 134,217,728

  prep_wih1<<<128, 256, 0, stream>>>(Wih1);

  if (ws_size >= 2*HBf){
    uint16_t* h0 = (uint16_t*)wsb;
    uint16_t* h1 = (uint16_t*)(wsb + HBf);
    float* scoresP = (float*)wsb;
    float* ctxP    = (float*)(wsb + (size_t)1024*TT*4);

    lstm0_kernel<<<256, 512, 0, stream>>>(x, ln_g, ln_b, Wih0, Whh0, bih0, bhh0,
                                          h0, 128, 1024, 0);
    if (useAgg)
      lstm1_agg <<<256, 512, 0, stream>>>(h0, Whh1, bih1, bhh1, h1, 128, 1024);
    else
      lstm1_safe<<<256, 512, 0, stream>>>(h0, Whh1, bih1, bhh1, h1, 128, 1024);
    scores_kernel<<<TT*16, 256, 0, stream>>>(h1, Wa1, ba1, Wa2, ba2, scoresP, 16, 1024);
    ctx_kernel   <<<1024, 256, 0, stream>>>(h1, scoresP, ctxP, 1024);
    head_kernel  <<<1024, 128, 0, stream>>>(ctxP, Wf1, bf1, ln2g, ln2b, Wf2, bf2, out, 0);
  } else {
    int BR = 512;
    while (BR > 64){
      size_t HB = (size_t)TT*BR*256*2;
      if (2*HB + 2*((size_t)BR*256*4) <= ws_size) break;
      BR >>= 1;
    }
    const size_t HB = (size_t)TT*BR*256*2;
    uint16_t* h0 = (uint16_t*)wsb;
    uint16_t* h1 = (uint16_t*)(wsb + HB);
    float* scoresP = (float*)(wsb + 2*HB);
    float* ctxP    = (float*)(wsb + 2*HB + (size_t)BR*256*4);
    const int nb = BR/NS;

    for (int b_off = 0; b_off < 1024; b_off += BR){
      lstm0_kernel<<<2*nb, 512, 0, stream>>>(x, ln_g, ln_b, Wih0, Whh0, bih0, bhh0,
                                             h0, nb, BR, b_off);
      if (useAgg)
        lstm1_agg <<<2*nb, 512, 0, stream>>>(h0, Whh1, bih1, bhh1, h1, nb, BR);
      else
        lstm1_safe<<<2*nb, 512, 0, stream>>>(h0, Whh1, bih1, bhh1, h1, nb, BR);
      scores_kernel<<<TT*(BR/64), 256, 0, stream>>>(h1, Wa1, ba1, Wa2, ba2, scoresP,
                                                    BR/64, BR);
      ctx_kernel   <<<BR, 256, 0, stream>>>(h1, scoresP, ctxP, BR);
      head_kernel  <<<BR, 128, 0, stream>>>(ctxP, Wf1, bf1, ln2g, ln2b, Wf2, bf2,
                                            out, b_off);
    }
  }
}

// Round 12
// 724.098 us; speedup vs baseline: 1.6740x; 1.0438x over previous
//
#include <hip/hip_runtime.h>
#include <stdint.h>

#define TT 256
#define NS 8
#define CH 8
#define L2E 1.4426950408889634f
#define L2E2 2.8853900817779268f

typedef __attribute__((ext_vector_type(4))) float f32x4;
typedef __attribute__((ext_vector_type(8))) short s16x8;
typedef __attribute__((ext_vector_type(2))) unsigned int u32x2;

#define DEV static __device__ __forceinline__

// prepped bf16 Wih1 fragments (exp2-scaled): [dir][ntg(32)][kt(8)][lane(64)][8]
__device__ uint16_t g_W1f[2*32*8*64*8];

DEV short f2bf(float f){
  union{float f; uint32_t u;} v; v.f = f;
  uint32_t r = v.u + 0x7fffu + ((v.u>>16)&1u);
  return (short)(r>>16);
}
DEV float bf2f(uint32_t u16){
  union{uint32_t u; float f;} v; v.u = u16<<16; return v.f;
}
DEV uint32_t pk2(float a, float b){
  return (uint32_t)(uint16_t)f2bf(a) | ((uint32_t)(uint16_t)f2bf(b)<<16);
}
DEV float rcpf(float x){ return __builtin_amdgcn_rcpf(x); }
DEV float exp2fast(float x){ return __builtin_amdgcn_exp2f(x); }
// gates arrive pre-scaled: sigmoid rows by L2E, tanh(g) rows by 2*L2E
DEV float sigm2(float x){ return rcpf(1.f + exp2fast(-x)); }
DEV float tanh2(float x){ return 1.f - 2.f*rcpf(exp2fast(x) + 1.f); }
DEV float tanhr(float x){ return 1.f - 2.f*rcpf(exp2fast(L2E2*x) + 1.f); }
DEV f32x4 MFMA(s16x8 a, s16x8 b, f32x4 c){
  return __builtin_amdgcn_mfma_f32_16x16x32_bf16(a, b, c, 0, 0, 0);
}
DEV s16x8 cvt8(const float* p){
  f32x4 a = *(const f32x4*)p;
  f32x4 b = *(const f32x4*)(p+4);
  s16x8 o;
  o[0]=f2bf(a[0]); o[1]=f2bf(a[1]); o[2]=f2bf(a[2]); o[3]=f2bf(a[3]);
  o[4]=f2bf(b[0]); o[5]=f2bf(b[1]); o[6]=f2bf(b[2]); o[7]=f2bf(b[3]);
  return o;
}
DEV s16x8 cvt8s(const float* p, float s){
  f32x4 a = *(const f32x4*)p;
  f32x4 b = *(const f32x4*)(p+4);
  s16x8 o;
  o[0]=f2bf(a[0]*s); o[1]=f2bf(a[1]*s); o[2]=f2bf(a[2]*s); o[3]=f2bf(a[3]*s);
  o[4]=f2bf(b[0]*s); o[5]=f2bf(b[1]*s); o[6]=f2bf(b[2]*s); o[7]=f2bf(b[3]*s);
  return o;
}
// barrier that drains LDS only (global stores/loads stay in flight)
DEV void bar_lds(){
  asm volatile("s_waitcnt lgkmcnt(0)" ::: "memory");
  __builtin_amdgcn_s_barrier();
}

// flush one step's h (8 rows x 128 cols bf16) straight from a 4KB hbuf frame.
DEV void flush_step(const short* hb, uint16_t* __restrict__ hdst, int tp,
                    int dir, int BR, int bg, int tid){
  if (tid < 128){
    int row = tid >> 4, part = tid & 15;
    int tg = dir ? (TT-1-tp) : tp;
    s16x8 v = *(const s16x8*)((const char*)hb + row*256 + (((part ^ row)&15)<<4));
    *(s16x8*)(hdst + ((size_t)tg*BR + bg*NS + row)*256 + dir*128 + part*8) = v;
  }
}

// ---------------- Wih1 -> bf16 B-fragment layout (exp2-scaled) ----------------
__global__ __launch_bounds__(256) void prep_wih1(const float* __restrict__ Wih1)
{
  int tid = blockIdx.x*256 + threadIdx.x;   // 32768 total
  int l = tid & 63, kt = (tid>>6)&7, ntg = (tid>>9)&31, dir = (tid>>14)&1;
  int lm = l&15, lk = l>>4;
  int n = ntg*16 + lm;
  float sc = ((ntg>>3) == 2) ? L2E2 : L2E;
  s16x8 o = cvt8s(Wih1 + ((size_t)(dir*512 + n))*256 + kt*32 + lk*8, sc);
  *(s16x8*)(&g_W1f[(size_t)tid*8]) = o;
}

// ================= BiLSTM layer 0 (LN fused; 6 -> 128/dir), NS=8 =================
__global__ __launch_bounds__(512,2) void lstm0_kernel(
    const float* __restrict__ x, const float* __restrict__ lng,
    const float* __restrict__ lnb,
    const float* __restrict__ Wih0, const float* __restrict__ Whh0,
    const float* __restrict__ bih0, const float* __restrict__ bhh0,
    uint16_t* __restrict__ h0, int nb, int BR, int b_off)
{
  const int dir = blockIdx.x / nb, bg = blockIdx.x % nb;
  const int tid = threadIdx.x, w = tid>>6, l = tid&63;
  const int lm = l&15, lk = l>>4;
  const int gb = b_off + bg*NS;

  __shared__ short hbuf[2][2048];     // 8 KB, XOR(row<<4) swizzle
  __shared__ short xnbf[TT*NS*8];     // 32 KB
  __shared__ short bxs[8*4*64*8];     // 32 KB

  for (int i=tid; i<4096; i+=512) ((short*)hbuf)[i] = 0;

  #pragma unroll
  for (int it=0; it<4; ++it){
    int pr = it*512 + tid;
    int r = pr >> 8, t = pr & 255;
    const float* px = x + ((size_t)(gb+r)*TT + t)*6;
    float v[6]; float mu=0.f, var=0.f;
    #pragma unroll
    for (int d=0; d<6; ++d){ v[d]=px[d]; mu+=v[d]; }
    mu *= (1.f/6.f);
    #pragma unroll
    for (int d=0; d<6; ++d){ float dd=v[d]-mu; var+=dd*dd; }
    float rs = rsqrtf(var*(1.f/6.f) + 1e-5f);
    s16x8 vv;
    #pragma unroll
    for (int d=0; d<6; ++d) vv[d] = f2bf((v[d]-mu)*rs*lng[d] + lnb[d]);
    vv[6]=0; vv[7]=0;
    *(s16x8*)&xnbf[(t*NS + r)*8] = vv;
  }

  const int c = w*16 + lm;
  s16x8 bw[4][4];
  float biasc[4];
  #pragma unroll
  for (int G=0; G<4; ++G){
    const float sc = (G==2) ? L2E2 : L2E;
    const int n = G*128 + c;
    biasc[G] = (bih0[dir*512+n] + bhh0[dir*512+n])*sc;
    #pragma unroll
    for (int kt=0; kt<4; ++kt)
      bw[G][kt] = cvt8s(Whh0 + ((size_t)(dir*512+n))*128 + kt*32 + lk*8, sc);
    s16x8 tx;
    #pragma unroll
    for (int j=0; j<8; ++j){
      int k = lk*8 + j;
      tx[j] = (k<6) ? f2bf(Wih0[(size_t)(dir*512+n)*6 + k]*sc) : (short)0;
    }
    *(s16x8*)&bxs[((w*4+G)*64 + l)*8] = tx;
  }

  const int r0 = ((l>>4)&1)*4 + ((l<32)?0:2);
  float cst[2] = {0.f, 0.f};
  __syncthreads();

  for (int t=0; t<TT; ++t){
    const int tt = dir ? (TT-1-t) : t;
    const int rd = t & 1;
    s16x8 ah[4];
    #pragma unroll
    for (int kt=0; kt<4; ++kt){
      int off = rd*4096 + lm*256 + ((kt*64 + lk*16) ^ (lm<<4));
      ah[kt] = *(const s16x8*)((const char*)hbuf + off);
    }
    s16x8 ax = {0,0,0,0,0,0,0,0};
    if (l < 8) ax = *(const s16x8*)&xnbf[(tt*NS + l)*8];

    f32x4 acc[4];
    #pragma unroll
    for (int G=0; G<4; ++G){
      f32x4 a = {0.f,0.f,0.f,0.f};
      #pragma unroll
      for (int kt=0; kt<4; ++kt) a = MFMA(ah[kt], bw[G][kt], a);
      s16x8 bx = *(const s16x8*)&bxs[((w*4+G)*64 + l)*8];
      a = MFMA(ax, bx, a);
      acc[G] = a;
    }

    float g0[4], g1[4];
    #pragma unroll
    for (int G=0; G<4; ++G){
      float o2 = __shfl(acc[G][2], l & 31);
      float o3 = __shfl(acc[G][3], l & 31);
      g0[G] = ((l<32) ? acc[G][0] : o2) + biasc[G];
      g1[G] = ((l<32) ? acc[G][1] : o3) + biasc[G];
    }
    float hv[2];
    {
      float cc = sigm2(g0[1])*cst[0] + sigm2(g0[0])*tanh2(g0[2]);
      cst[0] = cc; hv[0] = sigm2(g0[3])*tanhr(cc);
      cc = sigm2(g1[1])*cst[1] + sigm2(g1[0])*tanh2(g1[2]);
      cst[1] = cc; hv[1] = sigm2(g1[3])*tanhr(cc);
    }

    #pragma unroll
    for (int q=0; q<2; ++q){
      int r = r0 + q;
      *(short*)((char*)hbuf + (rd^1)*4096 + r*256 + ((c*2) ^ (r<<4))) = f2bf(hv[q]);
    }
    if (t > 0)
      flush_step(hbuf[rd], h0, t-1, dir, BR, bg, tid);
    bar_lds();
  }
  flush_step(hbuf[0], h0, TT-1, dir, BR, bg, tid);
}

// ============ BiLSTM layer 1 (256 -> 128/dir), fused xp, NS=8, CH=8 ============
__global__ __launch_bounds__(512,2) void lstm1_kernel(
    const uint16_t* __restrict__ h0,
    const float* __restrict__ Whh1, const float* __restrict__ bih1,
    const float* __restrict__ bhh1, uint16_t* __restrict__ h1,
    int nb, int BR)
{
  const int dir = blockIdx.x / nb, bg = blockIdx.x % nb;
  const int tid = threadIdx.x, w = tid>>6, l = tid&63;
  const int lm = l&15, lk = l>>4;

  __shared__ short hbuf[2][2048];
  __shared__ short abuf[2][16384];
  __shared__ u32x2 xpbuf[8192];

  for (int i=tid; i<4096; i+=512) ((short*)hbuf)[i] = 0;

  const int c = w*16 + lm;
  s16x8 bw[4][4];
  float biasv[4];
  #pragma unroll
  for (int G=0; G<4; ++G){
    const float sc = (G==2) ? L2E2 : L2E;
    const int n = G*128 + c;
    biasv[G] = (bih1[dir*512+n] + bhh1[dir*512+n])*sc;
    #pragma unroll
    for (int kt=0; kt<4; ++kt)
      bw[G][kt] = cvt8s(Whh1 + ((size_t)(dir*512+n))*128 + kt*32 + lk*8, sc);
  }

  const int r0 = ((l>>4)&1)*4 + ((l<32)?0:2);
  float cst[2] = {0.f,0.f};
  s16x8 vst[4];

  #pragma unroll
  for (int it=0; it<4; ++it){
    int sid = it*512 + tid, row = sid>>5, sl = sid&31, s = row>>3, b = row&7;
    int tg = dir ? (TT-1-s) : s;
    vst[it] = *(const s16x8*)(h0 + ((size_t)tg*BR + bg*NS + b)*256 + sl*8);
  }
  #pragma unroll
  for (int it=0; it<4; ++it){
    int sid = it*512 + tid, row = sid>>5, sl = sid&31;
    *(s16x8*)((char*)abuf + row*512 + ((sl ^ (row&15))<<4)) = vst[it];
  }
  __syncthreads();

  for (int ch=0; ch<TT/CH; ++ch){
    const int cur = ch & 1;
    const char* ab = (const char*)abuf + cur*32768;

    if (ch < TT/CH-1){
      #pragma unroll
      for (int it=0; it<4; ++it){
        int sid = it*512 + tid, row = sid>>5, sl = sid&31, s = row>>3, b = row&7;
        int ts = (ch+1)*CH + s;
        int tg = dir ? (TT-1-ts) : ts;
        vst[it] = *(const s16x8*)(h0 + ((size_t)tg*BR + bg*NS + b)*256 + sl*8);
      }
    }

    // ---- phase A: xp for CH steps -> LDS (scaled domain) ----
    #pragma unroll
    for (int G=0; G<4; ++G){
      f32x4 acc[4];
      #pragma unroll
      for (int mt=0; mt<4; ++mt) acc[mt] = (f32x4){biasv[G],biasv[G],biasv[G],biasv[G]};
      #pragma unroll
      for (int kt=0; kt<8; ++kt){
        s16x8 bfr = *(const s16x8*)(&g_W1f[(((size_t)(dir*32 + G*8 + w)*8 + kt)*64 + l)*8]);
        #pragma unroll
        for (int mt=0; mt<4; ++mt){
          int row = mt*16 + lm;
          s16x8 afr = *(const s16x8*)(ab + row*512 + (((kt*4+lk) ^ (row&15))<<4));
          acc[mt] = MFMA(afr, bfr, acc[mt]);
        }
      }
      #pragma unroll
      for (int mt=0; mt<4; ++mt){
        u32x2 pw;
        pw[0] = pk2(acc[mt][0], acc[mt][1]);
        pw[1] = pk2(acc[mt][2], acc[mt][3]);
        xpbuf[((w*4+G)*4+mt)*64 + l] = pw;
      }
    }

    if (ch < TT/CH-1){
      char* ab2 = (char*)abuf + (cur^1)*32768;
      #pragma unroll
      for (int it=0; it<4; ++it){
        int sid = it*512 + tid, row = sid>>5, sl = sid&31;
        *(s16x8*)(ab2 + row*512 + ((sl ^ (row&15))<<4)) = vst[it];
      }
    }
    bar_lds();

    // ---- phase B: CH recurrent steps ----
    #pragma unroll
    for (int s=0; s<CH; ++s){
      const int gs = ch*CH + s;
      const int rd = gs & 1;
      const int lane2 = ((((s&1)<<1) + lk)<<4) + lm;

      f32x4 acc4[4];
      #pragma unroll
      for (int G=0; G<4; ++G){
        u32x2 pw = xpbuf[((w*4+G)*4 + (s>>1))*64 + lane2];
        acc4[G] = (f32x4){bf2f(pw[0]&0xffffu), bf2f(pw[0]>>16),
                          bf2f(pw[1]&0xffffu), bf2f(pw[1]>>16)};
      }

      s16x8 ah[4];
      #pragma unroll
      for (int kt=0; kt<4; ++kt){
        int off = rd*4096 + lm*256 + ((kt*64 + lk*16) ^ (lm<<4));
        ah[kt] = *(const s16x8*)((const char*)hbuf + off);
      }
      #pragma unroll
      for (int G=0; G<4; ++G){
        #pragma unroll
        for (int kt=0; kt<4; ++kt)
          acc4[G] = MFMA(ah[kt], bw[G][kt], acc4[G]);
      }

      float g0[4], g1[4];
      #pragma unroll
      for (int G=0; G<4; ++G){
        float o2 = __shfl(acc4[G][2], l & 31);
        float o3 = __shfl(acc4[G][3], l & 31);
        g0[G] = (l<32) ? acc4[G][0] : o2;
        g1[G] = (l<32) ? acc4[G][1] : o3;
      }
      float hv[2];
      float cc = sigm2(g0[1])*cst[0] + sigm2(g0[0])*tanh2(g0[2]);
      cst[0] = cc; hv[0] = sigm2(g0[3])*tanhr(cc);
      cc = sigm2(g1[1])*cst[1] + sigm2(g1[0])*tanh2(g1[2]);
      cst[1] = cc; hv[1] = sigm2(g1[3])*tanhr(cc);

      #pragma unroll
      for (int q=0; q<2; ++q){
        int r = r0 + q;
        *(short*)((char*)hbuf + (rd^1)*4096 + r*256 + ((c*2) ^ (r<<4))) = f2bf(hv[q]);
      }
      if (gs > 0)
        flush_step(hbuf[rd], h1, gs-1, dir, BR, bg, tid);
      bar_lds();
    }
  }
  flush_step(hbuf[0], h1, TT-1, dir, BR, bg, tid);
}

// ========== fused attention: scores + softmax + context + LN head ==========
__global__ __launch_bounds__(256,2) void att_kernel(
    const uint16_t* __restrict__ h1,
    const float* __restrict__ Wa1, const float* __restrict__ ba1,
    const float* __restrict__ Wa2, const float* __restrict__ ba2,
    const float* __restrict__ Wf1, const float* __restrict__ bf1,
    const float* __restrict__ lg, const float* __restrict__ lb,
    const float* __restrict__ Wf2, const float* __restrict__ bf2v,
    float* __restrict__ out, int BR, int b_off)
{
  const int b = blockIdx.x;
  const int tid = threadIdx.x, w = tid>>6, l = tid&63;
  const int lm = l&15, lk = l>>4;

  __shared__ short abuf[64*256];      // 32 KB: 64 t-rows x 256 cols, swizzled
  __shared__ float sbuf[TT];          // scores -> attention weights
  __shared__ float scred[4][64];
  __shared__ float red[8];
  __shared__ float cbuf[256];
  __shared__ float zb[128];

  // Wa1 fragments: n = w*32 + nt*16 + lm
  s16x8 bwa[2][8]; float b1v[2], wa2v[2];
  #pragma unroll
  for (int nt=0; nt<2; ++nt){
    int n = w*32 + nt*16 + lm;
    b1v[nt] = ba1[n]; wa2v[nt] = Wa2[n];
    #pragma unroll
    for (int kt=0; kt<8; ++kt)
      bwa[nt][kt] = cvt8(Wa1 + (size_t)n*256 + kt*32 + lk*8);
  }

  // ---- pass 1: scores for all 256 t (4 tiles of 64 t-rows) ----
  for (int tb=0; tb<4; ++tb){
    const int t0 = tb*64;
    __syncthreads();                  // previous tile's MFMA reads done
    #pragma unroll
    for (int it=0; it<8; ++it){
      int sid = it*256 + tid, row = sid>>5, sl = sid&31;
      s16x8 v = *(const s16x8*)(h1 + ((size_t)(t0+row)*BR + b)*256 + sl*8);
      *(s16x8*)((char*)abuf + row*512 + ((sl ^ (row&15))<<4)) = v;
    }
    __syncthreads();

    #pragma unroll
    for (int mt=0; mt<4; ++mt){
      f32x4 a0 = {b1v[0],b1v[0],b1v[0],b1v[0]};
      f32x4 a1 = {b1v[1],b1v[1],b1v[1],b1v[1]};
      #pragma unroll
      for (int kt=0; kt<8; ++kt){
        int row = mt*16 + lm;
        s16x8 af = *(const s16x8*)((const char*)abuf + row*512 + (((kt*4+lk) ^ (row&15))<<4));
        a0 = MFMA(af, bwa[0][kt], a0);
        a1 = MFMA(af, bwa[1][kt], a1);
      }
      #pragma unroll
      for (int j=0; j<4; ++j){
        float pj = tanhr(a0[j])*wa2v[0] + tanhr(a1[j])*wa2v[1];
        #pragma unroll
        for (int m2=1; m2<16; m2<<=1) pj += __shfl_xor(pj, m2);
        if (lm == 0) scred[w][mt*16 + lk*4 + j] = pj;
      }
    }
    __syncthreads();
    if (tid < 64)
      sbuf[t0 + tid] = scred[0][tid]+scred[1][tid]+scred[2][tid]+scred[3][tid] + ba2[0];
  }
  __syncthreads();

  // ---- softmax over 256 t (thread owns t = tid) ----
  float scv = sbuf[tid];
  float m = scv;
  #pragma unroll
  for (int d=1; d<64; d<<=1) m = fmaxf(m, __shfl_xor(m, d));
  if (l == 0) red[w] = m;
  __syncthreads();
  m = fmaxf(fmaxf(red[0],red[1]), fmaxf(red[2],red[3]));
  float e = exp2fast(L2E*(scv - m));
  float ssum = e;
  #pragma unroll
  for (int d=1; d<64; d<<=1) ssum += __shfl_xor(ssum, d);
  if (l == 0) red[4+w] = ssum;
  __syncthreads();
  ssum = red[4]+red[5]+red[6]+red[7];
  sbuf[tid] = e * rcpf(ssum);
  __syncthreads();

  // ---- context: thread owns col c = tid ----
  float acc = 0.f;
  const uint16_t* hp = h1 + (size_t)b*256 + tid;
  #pragma unroll 8
  for (int t2=0; t2<TT; ++t2) acc += sbuf[t2] * bf2f(hp[(size_t)t2*BR*256]);
  cbuf[tid] = acc;
  __syncthreads();

  // ---- head: y = ctx @ Wf1^T + bf1; LN; relu; @ Wf2^T + bf2 ----
  float y = 0.f;
  if (tid < 128){
    y = bf1[tid];
    const float* wr = Wf1 + (size_t)tid*256;
    #pragma unroll 8
    for (int k=0; k<256; ++k) y += cbuf[k]*wr[k];
  }
  float s2 = y;
  #pragma unroll
  for (int d=1; d<64; d<<=1) s2 += __shfl_xor(s2, d);
  if (l == 0) red[w] = s2;
  __syncthreads();
  float mu = (red[0]+red[1]+red[2]+red[3])*(1.f/128.f);
  float dv = y - mu;
  float q = (tid < 128) ? dv*dv : 0.f;
  #pragma unroll
  for (int d=1; d<64; d<<=1) q += __shfl_xor(q, d);
  if (l == 0) red[4+w] = q;
  __syncthreads();
  float var = (red[4]+red[5]+red[6]+red[7])*(1.f/128.f);
  if (tid < 128){
    float z = dv*rsqrtf(var + 1e-5f)*lg[tid] + lb[tid];
    zb[tid] = fmaxf(z, 0.f);
  }
  __syncthreads();
  if (tid < 5){
    float o = bf2v[tid];
    const float* wp = Wf2 + (size_t)tid*128;
    for (int k=0; k<128; ++k) o += zb[k]*wp[k];
    out[(size_t)(b_off + b)*5 + tid] = o;
  }
}

extern "C" void kernel_launch(void* const* d_in, const int* in_sizes, int n_in,
                              void* d_out, int out_size, void* d_ws, size_t ws_size,
                              hipStream_t stream)
{
  const float* x    = (const float*)d_in[0];
  const float* ln_g = (const float*)d_in[1];
  const float* ln_b = (const float*)d_in[2];
  const float* Wih0 = (const float*)d_in[3];
  const float* Whh0 = (const float*)d_in[4];
  const float* bih0 = (const float*)d_in[5];
  const float* bhh0 = (const float*)d_in[6];
  const float* Wih1 = (const float*)d_in[7];
  const float* Whh1 = (const float*)d_in[8];
  const float* bih1 = (const float*)d_in[9];
  const float* bhh1 = (const float*)d_in[10];
  const float* Wa1  = (const float*)d_in[11];
  const float* ba1  = (const float*)d_in[12];
  const float* Wa2  = (const float*)d_in[13];
  const float* ba2  = (const float*)d_in[14];
  const float* Wf1  = (const float*)d_in[15];
  const float* bf1  = (const float*)d_in[16];
  const float* ln2g = (const float*)d_in[17];
  const float* ln2b = (const float*)d_in[18];
  const float* Wf2  = (const float*)d_in[19];
  const float* bf2  = (const float*)d_in[20];
  float* out = (float*)d_out;

  char* wsb = (char*)d_ws;
  const size_t HBf = (size_t)TT*1024*256*2;   // 134,217,728

  prep_wih1<<<128, 256, 0, stream>>>(Wih1);

  if (ws_size >= 2*HBf){
    // ---------- FULL: whole batch in one pass ----------
    uint16_t* h0 = (uint16_t*)wsb;
    uint16_t* h1 = (uint16_t*)(wsb + HBf);

    lstm0_kernel<<<256, 512, 0, stream>>>(x, ln_g, ln_b, Wih0, Whh0, bih0, bhh0,
                                          h0, 128, 1024, 0);
    lstm1_kernel<<<256, 512, 0, stream>>>(h0, Whh1, bih1, bhh1, h1, 128, 1024);
    att_kernel  <<<1024, 256, 0, stream>>>(h1, Wa1, ba1, Wa2, ba2, Wf1, bf1,
                                           ln2g, ln2b, Wf2, bf2, out, 1024, 0);
  } else {
    // ---------- fallback: rounds of BR samples ----------
    int BR = 512;
    while (BR > 64){
      size_t HB = (size_t)TT*BR*256*2;
      if (2*HB <= ws_size) break;
      BR >>= 1;
    }
    const size_t HB = (size_t)TT*BR*256*2;
    uint16_t* h0 = (uint16_t*)wsb;
    uint16_t* h1 = (uint16_t*)(wsb + HB);
    const int nb = BR/NS;

    for (int b_off = 0; b_off < 1024; b_off += BR){
      lstm0_kernel<<<2*nb, 512, 0, stream>>>(x, ln_g, ln_b, Wih0, Whh0, bih0, bhh0,
                                             h0, nb, BR, b_off);
      lstm1_kernel<<<2*nb, 512, 0, stream>>>(h0, Whh1, bih1, bhh1, h1, nb, BR);
      att_kernel  <<<BR, 256, 0, stream>>>(h1, Wa1, ba1, Wa2, ba2, Wf1, bf1,
                                           ln2g, ln2b, Wf2, bf2, out, BR, b_off);
    }
  }
}

// Round 13
// 723.549 us; speedup vs baseline: 1.6753x; 1.0008x over previous
//
#include <hip/hip_runtime.h>
#include <stdint.h>

#define TT 256
#define NS 8
#define CH 8
#define L2E 1.4426950408889634f
#define L2E2 2.8853900817779268f

typedef __attribute__((ext_vector_type(4))) float f32x4;
typedef __attribute__((ext_vector_type(8))) short s16x8;
typedef __attribute__((ext_vector_type(2))) unsigned int u32x2;

#define DEV static __device__ __forceinline__

// prepped bf16 Wih1 fragments (exp2-scaled): [dir][ntg(32)][kt(8)][lane(64)][8]
__device__ uint16_t g_W1f[2*32*8*64*8];

DEV short f2bf(float f){
  union{float f; uint32_t u;} v; v.f = f;
  uint32_t r = v.u + 0x7fffu + ((v.u>>16)&1u);
  return (short)(r>>16);
}
DEV float bf2f(uint32_t u16){
  union{uint32_t u; float f;} v; v.u = u16<<16; return v.f;
}
DEV uint32_t pk2(float a, float b){
  return (uint32_t)(uint16_t)f2bf(a) | ((uint32_t)(uint16_t)f2bf(b)<<16);
}
DEV float rcpf(float x){ return __builtin_amdgcn_rcpf(x); }
DEV float exp2fast(float x){ return __builtin_amdgcn_exp2f(x); }
DEV float sigm2(float x){ return rcpf(1.f + exp2fast(-x)); }
DEV float tanh2(float x){ return 1.f - 2.f*rcpf(exp2fast(x) + 1.f); }
DEV float tanhr(float x){ return 1.f - 2.f*rcpf(exp2fast(L2E2*x) + 1.f); }
DEV f32x4 MFMA(s16x8 a, s16x8 b, f32x4 c){
  return __builtin_amdgcn_mfma_f32_16x16x32_bf16(a, b, c, 0, 0, 0);
}
DEV s16x8 cvt8(const float* p){
  f32x4 a = *(const f32x4*)p;
  f32x4 b = *(const f32x4*)(p+4);
  s16x8 o;
  o[0]=f2bf(a[0]); o[1]=f2bf(a[1]); o[2]=f2bf(a[2]); o[3]=f2bf(a[3]);
  o[4]=f2bf(b[0]); o[5]=f2bf(b[1]); o[6]=f2bf(b[2]); o[7]=f2bf(b[3]);
  return o;
}
DEV s16x8 cvt8s(const float* p, float s){
  f32x4 a = *(const f32x4*)p;
  f32x4 b = *(const f32x4*)(p+4);
  s16x8 o;
  o[0]=f2bf(a[0]*s); o[1]=f2bf(a[1]*s); o[2]=f2bf(a[2]*s); o[3]=f2bf(a[3]*s);
  o[4]=f2bf(b[0]*s); o[5]=f2bf(b[1]*s); o[6]=f2bf(b[2]*s); o[7]=f2bf(b[3]*s);
  return o;
}
DEV void bar_lds(){
  asm volatile("s_waitcnt lgkmcnt(0)" ::: "memory");
  __builtin_amdgcn_s_barrier();
}

// flush one step's h (8 rows) from a 4KB hbuf frame (512-thr kernels).
DEV void flush_step(const short* hb, uint16_t* __restrict__ hdst, int tp,
                    int dir, int BR, int bg, int tid){
  if (tid < 128){
    int row = tid >> 4, part = tid & 15;
    int tg = dir ? (TT-1-tp) : tp;
    s16x8 v = *(const s16x8*)((const char*)hb + row*256 + (((part ^ row)&15)<<4));
    *(s16x8*)(hdst + ((size_t)tg*BR + bg*NS + row)*256 + dir*128 + part*8) = v;
  }
}
// flush one step's h (4 rows) — 256-thr NS=4 kernels.
DEV void flush_step4(const short* hb, uint16_t* __restrict__ hdst, int tp,
                     int dir, int BR, int bg, int tid){
  if (tid < 64){
    int row = tid >> 4, part = tid & 15;
    int tg = dir ? (TT-1-tp) : tp;
    s16x8 v = *(const s16x8*)((const char*)hb + row*256 + (((part ^ row)&15)<<4));
    *(s16x8*)(hdst + ((size_t)tg*BR + bg*4 + row)*256 + dir*128 + part*8) = v;
  }
}

// ---------------- Wih1 -> bf16 B-fragment layout (exp2-scaled) ----------------
__global__ __launch_bounds__(256) void prep_wih1(const float* __restrict__ Wih1)
{
  int tid = blockIdx.x*256 + threadIdx.x;
  int l = tid & 63, kt = (tid>>6)&7, ntg = (tid>>9)&31, dir = (tid>>14)&1;
  int lm = l&15, lk = l>>4;
  int n = ntg*16 + lm;
  float sc = ((ntg>>3) == 2) ? L2E2 : L2E;
  s16x8 o = cvt8s(Wih1 + ((size_t)(dir*512 + n))*256 + kt*32 + lk*8, sc);
  *(s16x8*)(&g_W1f[(size_t)tid*8]) = o;
}

// ================= narrow (512-thr) lstm0, NS=8 — round-12 fallback =================
__global__ __launch_bounds__(512,2) void lstm0_kernel(
    const float* __restrict__ x, const float* __restrict__ lng,
    const float* __restrict__ lnb,
    const float* __restrict__ Wih0, const float* __restrict__ Whh0,
    const float* __restrict__ bih0, const float* __restrict__ bhh0,
    uint16_t* __restrict__ h0, int nb, int BR, int b_off)
{
  const int dir = blockIdx.x / nb, bg = blockIdx.x % nb;
  const int tid = threadIdx.x, w = tid>>6, l = tid&63;
  const int lm = l&15, lk = l>>4;
  const int gb = b_off + bg*NS;

  __shared__ short hbuf[2][2048];
  __shared__ short xnbf[TT*NS*8];
  __shared__ short bxs[8*4*64*8];

  for (int i=tid; i<4096; i+=512) ((short*)hbuf)[i] = 0;

  #pragma unroll
  for (int it=0; it<4; ++it){
    int pr = it*512 + tid;
    int r = pr >> 8, t = pr & 255;
    const float* px = x + ((size_t)(gb+r)*TT + t)*6;
    float v[6]; float mu=0.f, var=0.f;
    #pragma unroll
    for (int d=0; d<6; ++d){ v[d]=px[d]; mu+=v[d]; }
    mu *= (1.f/6.f);
    #pragma unroll
    for (int d=0; d<6; ++d){ float dd=v[d]-mu; var+=dd*dd; }
    float rs = rsqrtf(var*(1.f/6.f) + 1e-5f);
    s16x8 vv;
    #pragma unroll
    for (int d=0; d<6; ++d) vv[d] = f2bf((v[d]-mu)*rs*lng[d] + lnb[d]);
    vv[6]=0; vv[7]=0;
    *(s16x8*)&xnbf[(t*NS + r)*8] = vv;
  }

  const int c = w*16 + lm;
  s16x8 bw[4][4];
  float biasc[4];
  #pragma unroll
  for (int G=0; G<4; ++G){
    const float sc = (G==2) ? L2E2 : L2E;
    const int n = G*128 + c;
    biasc[G] = (bih0[dir*512+n] + bhh0[dir*512+n])*sc;
    #pragma unroll
    for (int kt=0; kt<4; ++kt)
      bw[G][kt] = cvt8s(Whh0 + ((size_t)(dir*512+n))*128 + kt*32 + lk*8, sc);
    s16x8 tx;
    #pragma unroll
    for (int j=0; j<8; ++j){
      int k = lk*8 + j;
      tx[j] = (k<6) ? f2bf(Wih0[(size_t)(dir*512+n)*6 + k]*sc) : (short)0;
    }
    *(s16x8*)&bxs[((w*4+G)*64 + l)*8] = tx;
  }

  const int r0 = ((l>>4)&1)*4 + ((l<32)?0:2);
  float cst[2] = {0.f, 0.f};
  __syncthreads();

  for (int t=0; t<TT; ++t){
    const int tt = dir ? (TT-1-t) : t;
    const int rd = t & 1;
    s16x8 ah[4];
    #pragma unroll
    for (int kt=0; kt<4; ++kt){
      int off = rd*4096 + lm*256 + ((kt*64 + lk*16) ^ (lm<<4));
      ah[kt] = *(const s16x8*)((const char*)hbuf + off);
    }
    s16x8 ax = {0,0,0,0,0,0,0,0};
    if (l < 8) ax = *(const s16x8*)&xnbf[(tt*NS + l)*8];

    f32x4 acc[4];
    #pragma unroll
    for (int G=0; G<4; ++G){
      f32x4 a = {0.f,0.f,0.f,0.f};
      #pragma unroll
      for (int kt=0; kt<4; ++kt) a = MFMA(ah[kt], bw[G][kt], a);
      s16x8 bx = *(const s16x8*)&bxs[((w*4+G)*64 + l)*8];
      a = MFMA(ax, bx, a);
      acc[G] = a;
    }

    float g0[4], g1[4];
    #pragma unroll
    for (int G=0; G<4; ++G){
      float o2 = __shfl(acc[G][2], l & 31);
      float o3 = __shfl(acc[G][3], l & 31);
      g0[G] = ((l<32) ? acc[G][0] : o2) + biasc[G];
      g1[G] = ((l<32) ? acc[G][1] : o3) + biasc[G];
    }
    float hv[2];
    {
      float cc = sigm2(g0[1])*cst[0] + sigm2(g0[0])*tanh2(g0[2]);
      cst[0] = cc; hv[0] = sigm2(g0[3])*tanhr(cc);
      cc = sigm2(g1[1])*cst[1] + sigm2(g1[0])*tanh2(g1[2]);
      cst[1] = cc; hv[1] = sigm2(g1[3])*tanhr(cc);
    }

    #pragma unroll
    for (int q=0; q<2; ++q){
      int r = r0 + q;
      *(short*)((char*)hbuf + (rd^1)*4096 + r*256 + ((c*2) ^ (r<<4))) = f2bf(hv[q]);
    }
    if (t > 0)
      flush_step(hbuf[rd], h0, t-1, dir, BR, bg, tid);
    bar_lds();
  }
  flush_step(hbuf[0], h0, TT-1, dir, BR, bg, tid);
}

// ================= narrow (512-thr) lstm1, NS=8, CH=8 — round-12 fallback =================
__global__ __launch_bounds__(512,2) void lstm1_kernel(
    const uint16_t* __restrict__ h0,
    const float* __restrict__ Whh1, const float* __restrict__ bih1,
    const float* __restrict__ bhh1, uint16_t* __restrict__ h1,
    int nb, int BR)
{
  const int dir = blockIdx.x / nb, bg = blockIdx.x % nb;
  const int tid = threadIdx.x, w = tid>>6, l = tid&63;
  const int lm = l&15, lk = l>>4;

  __shared__ short hbuf[2][2048];
  __shared__ short abuf[2][16384];
  __shared__ u32x2 xpbuf[8192];

  for (int i=tid; i<4096; i+=512) ((short*)hbuf)[i] = 0;

  const int c = w*16 + lm;
  s16x8 bw[4][4];
  float biasv[4];
  #pragma unroll
  for (int G=0; G<4; ++G){
    const float sc = (G==2) ? L2E2 : L2E;
    const int n = G*128 + c;
    biasv[G] = (bih1[dir*512+n] + bhh1[dir*512+n])*sc;
    #pragma unroll
    for (int kt=0; kt<4; ++kt)
      bw[G][kt] = cvt8s(Whh1 + ((size_t)(dir*512+n))*128 + kt*32 + lk*8, sc);
  }

  const int r0 = ((l>>4)&1)*4 + ((l<32)?0:2);
  float cst[2] = {0.f,0.f};
  s16x8 vst[4];

  #pragma unroll
  for (int it=0; it<4; ++it){
    int sid = it*512 + tid, row = sid>>5, sl = sid&31, s = row>>3, b = row&7;
    int tg = dir ? (TT-1-s) : s;
    vst[it] = *(const s16x8*)(h0 + ((size_t)tg*BR + bg*NS + b)*256 + sl*8);
  }
  #pragma unroll
  for (int it=0; it<4; ++it){
    int sid = it*512 + tid, row = sid>>5, sl = sid&31;
    *(s16x8*)((char*)abuf + row*512 + ((sl ^ (row&15))<<4)) = vst[it];
  }
  __syncthreads();

  for (int ch=0; ch<TT/CH; ++ch){
    const int cur = ch & 1;
    const char* ab = (const char*)abuf + cur*32768;

    if (ch < TT/CH-1){
      #pragma unroll
      for (int it=0; it<4; ++it){
        int sid = it*512 + tid, row = sid>>5, sl = sid&31, s = row>>3, b = row&7;
        int ts = (ch+1)*CH + s;
        int tg = dir ? (TT-1-ts) : ts;
        vst[it] = *(const s16x8*)(h0 + ((size_t)tg*BR + bg*NS + b)*256 + sl*8);
      }
    }

    #pragma unroll
    for (int G=0; G<4; ++G){
      f32x4 acc[4];
      #pragma unroll
      for (int mt=0; mt<4; ++mt) acc[mt] = (f32x4){biasv[G],biasv[G],biasv[G],biasv[G]};
      #pragma unroll
      for (int kt=0; kt<8; ++kt){
        s16x8 bfr = *(const s16x8*)(&g_W1f[(((size_t)(dir*32 + G*8 + w)*8 + kt)*64 + l)*8]);
        #pragma unroll
        for (int mt=0; mt<4; ++mt){
          int row = mt*16 + lm;
          s16x8 afr = *(const s16x8*)(ab + row*512 + (((kt*4+lk) ^ (row&15))<<4));
          acc[mt] = MFMA(afr, bfr, acc[mt]);
        }
      }
      #pragma unroll
      for (int mt=0; mt<4; ++mt){
        u32x2 pw;
        pw[0] = pk2(acc[mt][0], acc[mt][1]);
        pw[1] = pk2(acc[mt][2], acc[mt][3]);
        xpbuf[((w*4+G)*4+mt)*64 + l] = pw;
      }
    }

    if (ch < TT/CH-1){
      char* ab2 = (char*)abuf + (cur^1)*32768;
      #pragma unroll
      for (int it=0; it<4; ++it){
        int sid = it*512 + tid, row = sid>>5, sl = sid&31;
        *(s16x8*)(ab2 + row*512 + ((sl ^ (row&15))<<4)) = vst[it];
      }
    }
    bar_lds();

    #pragma unroll
    for (int s=0; s<CH; ++s){
      const int gs = ch*CH + s;
      const int rd = gs & 1;
      const int lane2 = ((((s&1)<<1) + lk)<<4) + lm;

      f32x4 acc4[4];
      #pragma unroll
      for (int G=0; G<4; ++G){
        u32x2 pw = xpbuf[((w*4+G)*4 + (s>>1))*64 + lane2];
        acc4[G] = (f32x4){bf2f(pw[0]&0xffffu), bf2f(pw[0]>>16),
                          bf2f(pw[1]&0xffffu), bf2f(pw[1]>>16)};
      }

      s16x8 ah[4];
      #pragma unroll
      for (int kt=0; kt<4; ++kt){
        int off = rd*4096 + lm*256 + ((kt*64 + lk*16) ^ (lm<<4));
        ah[kt] = *(const s16x8*)((const char*)hbuf + off);
      }
      #pragma unroll
      for (int G=0; G<4; ++G){
        #pragma unroll
        for (int kt=0; kt<4; ++kt)
          acc4[G] = MFMA(ah[kt], bw[G][kt], acc4[G]);
      }

      float g0[4], g1[4];
      #pragma unroll
      for (int G=0; G<4; ++G){
        float o2 = __shfl(acc4[G][2], l & 31);
        float o3 = __shfl(acc4[G][3], l & 31);
        g0[G] = (l<32) ? acc4[G][0] : o2;
        g1[G] = (l<32) ? acc4[G][1] : o3;
      }
      float hv[2];
      float cc = sigm2(g0[1])*cst[0] + sigm2(g0[0])*tanh2(g0[2]);
      cst[0] = cc; hv[0] = sigm2(g0[3])*tanhr(cc);
      cc = sigm2(g1[1])*cst[1] + sigm2(g1[0])*tanh2(g1[2]);
      cst[1] = cc; hv[1] = sigm2(g1[3])*tanhr(cc);

      #pragma unroll
      for (int q=0; q<2; ++q){
        int r = r0 + q;
        *(short*)((char*)hbuf + (rd^1)*4096 + r*256 + ((c*2) ^ (r<<4))) = f2bf(hv[q]);
      }
      if (gs > 0)
        flush_step(hbuf[rd], h1, gs-1, dir, BR, bg, tid);
      bar_lds();
    }
  }
  flush_step(hbuf[0], h1, TT-1, dir, BR, bg, tid);
}

// ================= WIDE lstm0: 256 threads, NS=4, 2 col-groups/wave =================
__global__ __launch_bounds__(256,1) void lstm0_wide(
    const float* __restrict__ x, const float* __restrict__ lng,
    const float* __restrict__ lnb,
    const float* __restrict__ Wih0, const float* __restrict__ Whh0,
    const float* __restrict__ bih0, const float* __restrict__ bhh0,
    uint16_t* __restrict__ h0, int nb, int BR, int b_off)
{
  const int dir = blockIdx.x / nb, bg = blockIdx.x % nb;
  const int tid = threadIdx.x, w = tid>>6, l = tid&63;
  const int lm = l&15, lk = l>>4;
  const int gb = b_off + bg*4;

  __shared__ short hbuf[2][2048];     // 8 KB (rows 4-15 zero)
  __shared__ short xnbf[TT*4*8];      // 16 KB
  __shared__ short bxs[8*4*64*8];     // 32 KB

  for (int i=tid; i<4096; i+=256) ((short*)hbuf)[i] = 0;

  #pragma unroll
  for (int it=0; it<4; ++it){
    int pr = it*256 + tid;
    int r = pr >> 8, t = pr & 255;
    const float* px = x + ((size_t)(gb+r)*TT + t)*6;
    float v[6]; float mu=0.f, var=0.f;
    #pragma unroll
    for (int d=0; d<6; ++d){ v[d]=px[d]; mu+=v[d]; }
    mu *= (1.f/6.f);
    #pragma unroll
    for (int d=0; d<6; ++d){ float dd=v[d]-mu; var+=dd*dd; }
    float rs = rsqrtf(var*(1.f/6.f) + 1e-5f);
    s16x8 vv;
    #pragma unroll
    for (int d=0; d<6; ++d) vv[d] = f2bf((v[d]-mu)*rs*lng[d] + lnb[d]);
    vv[6]=0; vv[7]=0;
    *(s16x8*)&xnbf[(t*4 + r)*8] = vv;
  }

  int cc2[2];
  s16x8 bw[2][4][4];
  float biasc[2][4];
  #pragma unroll
  for (int cg=0; cg<2; ++cg){
    const int cgid = w + cg*4;
    const int c = cgid*16 + lm;
    cc2[cg] = c;
    #pragma unroll
    for (int G=0; G<4; ++G){
      const float sc = (G==2) ? L2E2 : L2E;
      const int n = G*128 + c;
      biasc[cg][G] = (bih0[dir*512+n] + bhh0[dir*512+n])*sc;
      #pragma unroll
      for (int kt=0; kt<4; ++kt)
        bw[cg][G][kt] = cvt8s(Whh0 + ((size_t)(dir*512+n))*128 + kt*32 + lk*8, sc);
      s16x8 tx;
      #pragma unroll
      for (int j=0; j<8; ++j){
        int k = lk*8 + j;
        tx[j] = (k<6) ? f2bf(Wih0[(size_t)(dir*512+n)*6 + k]*sc) : (short)0;
      }
      *(s16x8*)&bxs[((cgid*4+G)*64 + l)*8] = tx;
    }
  }

  const int r0 = ((l>>4)&1)*4 + ((l<32)?0:2);
  float cst[2][2] = {{0.f,0.f},{0.f,0.f}};
  __syncthreads();

  for (int t=0; t<TT; ++t){
    const int tt = dir ? (TT-1-t) : t;
    const int rd = t & 1;
    s16x8 ah[4];
    #pragma unroll
    for (int kt=0; kt<4; ++kt){
      int off = rd*4096 + lm*256 + ((kt*64 + lk*16) ^ (lm<<4));
      ah[kt] = *(const s16x8*)((const char*)hbuf + off);
    }
    s16x8 ax = {0,0,0,0,0,0,0,0};
    if (l < 4) ax = *(const s16x8*)&xnbf[(tt*4 + l)*8];

    #pragma unroll
    for (int cg=0; cg<2; ++cg){
      const int cgid = w + cg*4;
      f32x4 acc[4];
      #pragma unroll
      for (int G=0; G<4; ++G){
        f32x4 a = {0.f,0.f,0.f,0.f};
        #pragma unroll
        for (int kt=0; kt<4; ++kt) a = MFMA(ah[kt], bw[cg][G][kt], a);
        s16x8 bx = *(const s16x8*)&bxs[((cgid*4+G)*64 + l)*8];
        a = MFMA(ax, bx, a);
        acc[G] = a;
      }
      float g0[4], g1[4];
      #pragma unroll
      for (int G=0; G<4; ++G){
        float o2 = __shfl(acc[G][2], l & 31);
        float o3 = __shfl(acc[G][3], l & 31);
        g0[G] = ((l<32) ? acc[G][0] : o2) + biasc[cg][G];
        g1[G] = ((l<32) ? acc[G][1] : o3) + biasc[cg][G];
      }
      float c0 = sigm2(g0[1])*cst[cg][0] + sigm2(g0[0])*tanh2(g0[2]);
      cst[cg][0] = c0;
      float hv0 = sigm2(g0[3])*tanhr(c0);
      float c1 = sigm2(g1[1])*cst[cg][1] + sigm2(g1[0])*tanh2(g1[2]);
      cst[cg][1] = c1;
      float hv1 = sigm2(g1[3])*tanhr(c1);

      if (r0 < 4){
        const int c = cc2[cg];
        *(short*)((char*)hbuf + (rd^1)*4096 + r0*256 + ((c*2) ^ (r0<<4))) = f2bf(hv0);
        int r = r0+1;
        *(short*)((char*)hbuf + (rd^1)*4096 + r*256 + ((c*2) ^ (r<<4))) = f2bf(hv1);
      }
    }
    if (t > 0)
      flush_step4(hbuf[rd], h0, t-1, dir, BR, bg, tid);
    bar_lds();
  }
  flush_step4(hbuf[0], h0, TT-1, dir, BR, bg, tid);
}

// ================= WIDE lstm1: 256 threads, NS=4, CH=8, 2 col-groups/wave =================
__global__ __launch_bounds__(256,1) void lstm1_wide(
    const uint16_t* __restrict__ h0,
    const float* __restrict__ Whh1, const float* __restrict__ bih1,
    const float* __restrict__ bhh1, uint16_t* __restrict__ h1,
    int nb, int BR)
{
  const int dir = blockIdx.x / nb, bg = blockIdx.x % nb;
  const int tid = threadIdx.x, w = tid>>6, l = tid&63;
  const int lm = l&15, lk = l>>4;

  __shared__ short hbuf[2][2048];     // 8 KB
  __shared__ short abuf[2][8192];     // 32 KB: 32 rows x 256 cols, dbuf
  __shared__ u32x2 xpbuf[4096];       // 32 KB: [cgid(8)][G][mt(2)][lane]

  for (int i=tid; i<4096; i+=256) ((short*)hbuf)[i] = 0;

  int cc2[2];
  s16x8 bw[2][4][4];
  float biasv[2][4];
  #pragma unroll
  for (int cg=0; cg<2; ++cg){
    const int c = (w + cg*4)*16 + lm;
    cc2[cg] = c;
    #pragma unroll
    for (int G=0; G<4; ++G){
      const float sc = (G==2) ? L2E2 : L2E;
      const int n = G*128 + c;
      biasv[cg][G] = (bih1[dir*512+n] + bhh1[dir*512+n])*sc;
      #pragma unroll
      for (int kt=0; kt<4; ++kt)
        bw[cg][G][kt] = cvt8s(Whh1 + ((size_t)(dir*512+n))*128 + kt*32 + lk*8, sc);
    }
  }

  const int r0 = ((l>>4)&1)*4 + ((l<32)?0:2);
  float cst[2][2] = {{0.f,0.f},{0.f,0.f}};
  s16x8 vst[4];

  // prologue: stage chunk 0 (32 rows = s*4 + b)
  #pragma unroll
  for (int it=0; it<4; ++it){
    int sid = it*256 + tid, row = sid>>5, sl = sid&31, s = row>>2, b = row&3;
    int tg = dir ? (TT-1-s) : s;
    vst[it] = *(const s16x8*)(h0 + ((size_t)tg*BR + bg*4 + b)*256 + sl*8);
  }
  #pragma unroll
  for (int it=0; it<4; ++it){
    int sid = it*256 + tid, row = sid>>5, sl = sid&31;
    *(s16x8*)((char*)abuf + row*512 + ((sl ^ (row&15))<<4)) = vst[it];
  }
  __syncthreads();

  for (int ch=0; ch<TT/CH; ++ch){
    const int cur = ch & 1;
    const char* ab = (const char*)abuf + cur*16384;

    if (ch < TT/CH-1){
      #pragma unroll
      for (int it=0; it<4; ++it){
        int sid = it*256 + tid, row = sid>>5, sl = sid&31, s = row>>2, b = row&3;
        int ts = (ch+1)*CH + s;
        int tg = dir ? (TT-1-ts) : ts;
        vst[it] = *(const s16x8*)(h0 + ((size_t)tg*BR + bg*4 + b)*256 + sl*8);
      }
    }

    // ---- phase A: xp for CH steps -> LDS ----
    #pragma unroll
    for (int cg=0; cg<2; ++cg){
      const int cgid = w + cg*4;
      #pragma unroll
      for (int G=0; G<4; ++G){
        f32x4 acc[2];
        #pragma unroll
        for (int mt=0; mt<2; ++mt)
          acc[mt] = (f32x4){biasv[cg][G],biasv[cg][G],biasv[cg][G],biasv[cg][G]};
        #pragma unroll
        for (int kt=0; kt<8; ++kt){
          s16x8 bfr = *(const s16x8*)(&g_W1f[(((size_t)(dir*32 + G*8 + cgid)*8 + kt)*64 + l)*8]);
          #pragma unroll
          for (int mt=0; mt<2; ++mt){
            int row = mt*16 + lm;
            s16x8 afr = *(const s16x8*)(ab + row*512 + (((kt*4+lk) ^ (row&15))<<4));
            acc[mt] = MFMA(afr, bfr, acc[mt]);
          }
        }
        #pragma unroll
        for (int mt=0; mt<2; ++mt){
          u32x2 pw;
          pw[0] = pk2(acc[mt][0], acc[mt][1]);
          pw[1] = pk2(acc[mt][2], acc[mt][3]);
          xpbuf[((cgid*4+G)*2+mt)*64 + l] = pw;
        }
      }
    }

    if (ch < TT/CH-1){
      char* ab2 = (char*)abuf + (cur^1)*16384;
      #pragma unroll
      for (int it=0; it<4; ++it){
        int sid = it*256 + tid, row = sid>>5, sl = sid&31;
        *(s16x8*)(ab2 + row*512 + ((sl ^ (row&15))<<4)) = vst[it];
      }
    }
    bar_lds();

    // ---- phase B: CH recurrent steps ----
    #pragma unroll
    for (int s=0; s<CH; ++s){
      const int gs = ch*CH + s;
      const int rd = gs & 1;
      // xp for samples b=0..3 of step s: tile mt=s>>2, holder lane ((s&3)<<4)+lm,
      // 4 packed words = b 0..3 directly (C rows j = b).
      const int lane2 = ((s&3)<<4) + lm;
      const int mt = s>>2;

      s16x8 ah[4];
      #pragma unroll
      for (int kt=0; kt<4; ++kt){
        int off = rd*4096 + lm*256 + ((kt*64 + lk*16) ^ (lm<<4));
        ah[kt] = *(const s16x8*)((const char*)hbuf + off);
      }

      #pragma unroll
      for (int cg=0; cg<2; ++cg){
        const int cgid = w + cg*4;
        f32x4 acc4[4];
        #pragma unroll
        for (int G=0; G<4; ++G){
          u32x2 pw = xpbuf[((cgid*4+G)*2 + mt)*64 + lane2];
          acc4[G] = (f32x4){bf2f(pw[0]&0xffffu), bf2f(pw[0]>>16),
                            bf2f(pw[1]&0xffffu), bf2f(pw[1]>>16)};
          #pragma unroll
          for (int kt=0; kt<4; ++kt)
            acc4[G] = MFMA(ah[kt], bw[cg][G][kt], acc4[G]);
        }

        float g0[4], g1[4];
        #pragma unroll
        for (int G=0; G<4; ++G){
          float o2 = __shfl(acc4[G][2], l & 31);
          float o3 = __shfl(acc4[G][3], l & 31);
          g0[G] = (l<32) ? acc4[G][0] : o2;
          g1[G] = (l<32) ? acc4[G][1] : o3;
        }
        float c0 = sigm2(g0[1])*cst[cg][0] + sigm2(g0[0])*tanh2(g0[2]);
        cst[cg][0] = c0;
        float hv0 = sigm2(g0[3])*tanhr(c0);
        float c1 = sigm2(g1[1])*cst[cg][1] + sigm2(g1[0])*tanh2(g1[2]);
        cst[cg][1] = c1;
        float hv1 = sigm2(g1[3])*tanhr(c1);

        if (r0 < 4){
          const int c = cc2[cg];
          *(short*)((char*)hbuf + (rd^1)*4096 + r0*256 + ((c*2) ^ (r0<<4))) = f2bf(hv0);
          int r = r0+1;
          *(short*)((char*)hbuf + (rd^1)*4096 + r*256 + ((c*2) ^ (r<<4))) = f2bf(hv1);
        }
      }
      if (gs > 0)
        flush_step4(hbuf[rd], h1, gs-1, dir, BR, bg, tid);
      bar_lds();
    }
  }
  flush_step4(hbuf[0], h1, TT-1, dir, BR, bg, tid);
}

// ========== fused attention: scores + softmax + context + LN head ==========
__global__ __launch_bounds__(256,2) void att_kernel(
    const uint16_t* __restrict__ h1,
    const float* __restrict__ Wa1, const float* __restrict__ ba1,
    const float* __restrict__ Wa2, const float* __restrict__ ba2,
    const float* __restrict__ Wf1, const float* __restrict__ bf1,
    const float* __restrict__ lg, const float* __restrict__ lb,
    const float* __restrict__ Wf2, const float* __restrict__ bf2v,
    float* __restrict__ out, int BR, int b_off)
{
  const int b = blockIdx.x;
  const int tid = threadIdx.x, w = tid>>6, l = tid&63;
  const int lm = l&15, lk = l>>4;

  __shared__ short abuf[64*256];
  __shared__ float sbuf[TT];
  __shared__ float scred[4][64];
  __shared__ float red[8];
  __shared__ float cbuf[256];
  __shared__ float zb[128];

  s16x8 bwa[2][8]; float b1v[2], wa2v[2];
  #pragma unroll
  for (int nt=0; nt<2; ++nt){
    int n = w*32 + nt*16 + lm;
    b1v[nt] = ba1[n]; wa2v[nt] = Wa2[n];
    #pragma unroll
    for (int kt=0; kt<8; ++kt)
      bwa[nt][kt] = cvt8(Wa1 + (size_t)n*256 + kt*32 + lk*8);
  }

  for (int tb=0; tb<4; ++tb){
    const int t0 = tb*64;
    __syncthreads();
    #pragma unroll
    for (int it=0; it<8; ++it){
      int sid = it*256 + tid, row = sid>>5, sl = sid&31;
      s16x8 v = *(const s16x8*)(h1 + ((size_t)(t0+row)*BR + b)*256 + sl*8);
      *(s16x8*)((char*)abuf + row*512 + ((sl ^ (row&15))<<4)) = v;
    }
    __syncthreads();

    #pragma unroll
    for (int mt=0; mt<4; ++mt){
      f32x4 a0 = {b1v[0],b1v[0],b1v[0],b1v[0]};
      f32x4 a1 = {b1v[1],b1v[1],b1v[1],b1v[1]};
      #pragma unroll
      for (int kt=0; kt<8; ++kt){
        int row = mt*16 + lm;
        s16x8 af = *(const s16x8*)((const char*)abuf + row*512 + (((kt*4+lk) ^ (row&15))<<4));
        a0 = MFMA(af, bwa[0][kt], a0);
        a1 = MFMA(af, bwa[1][kt], a1);
      }
      #pragma unroll
      for (int j=0; j<4; ++j){
        float pj = tanhr(a0[j])*wa2v[0] + tanhr(a1[j])*wa2v[1];
        #pragma unroll
        for (int m2=1; m2<16; m2<<=1) pj += __shfl_xor(pj, m2);
        if (lm == 0) scred[w][mt*16 + lk*4 + j] = pj;
      }
    }
    __syncthreads();
    if (tid < 64)
      sbuf[t0 + tid] = scred[0][tid]+scred[1][tid]+scred[2][tid]+scred[3][tid] + ba2[0];
  }
  __syncthreads();

  float scv = sbuf[tid];
  float m = scv;
  #pragma unroll
  for (int d=1; d<64; d<<=1) m = fmaxf(m, __shfl_xor(m, d));
  if (l == 0) red[w] = m;
  __syncthreads();
  m = fmaxf(fmaxf(red[0],red[1]), fmaxf(red[2],red[3]));
  float e = exp2fast(L2E*(scv - m));
  float ssum = e;
  #pragma unroll
  for (int d=1; d<64; d<<=1) ssum += __shfl_xor(ssum, d);
  if (l == 0) red[4+w] = ssum;
  __syncthreads();
  ssum = red[4]+red[5]+red[6]+red[7];
  sbuf[tid] = e * rcpf(ssum);
  __syncthreads();

  float acc = 0.f;
  const uint16_t* hp = h1 + (size_t)b*256 + tid;
  #pragma unroll 8
  for (int t2=0; t2<TT; ++t2) acc += sbuf[t2] * bf2f(hp[(size_t)t2*BR*256]);
  cbuf[tid] = acc;
  __syncthreads();

  float y = 0.f;
  if (tid < 128){
    y = bf1[tid];
    const float* wr = Wf1 + (size_t)tid*256;
    #pragma unroll 8
    for (int k=0; k<256; ++k) y += cbuf[k]*wr[k];
  }
  float s2 = y;
  #pragma unroll
  for (int d=1; d<64; d<<=1) s2 += __shfl_xor(s2, d);
  if (l == 0) red[w] = s2;
  __syncthreads();
  float mu = (red[0]+red[1]+red[2]+red[3])*(1.f/128.f);
  float dv = y - mu;
  float q = (tid < 128) ? dv*dv : 0.f;
  #pragma unroll
  for (int d=1; d<64; d<<=1) q += __shfl_xor(q, d);
  if (l == 0) red[4+w] = q;
  __syncthreads();
  float var = (red[4]+red[5]+red[6]+red[7])*(1.f/128.f);
  if (tid < 128){
    float z = dv*rsqrtf(var + 1e-5f)*lg[tid] + lb[tid];
    zb[tid] = fmaxf(z, 0.f);
  }
  __syncthreads();
  if (tid < 5){
    float o = bf2v[tid];
    const float* wp = Wf2 + (size_t)tid*128;
    for (int k=0; k<128; ++k) o += zb[k]*wp[k];
    out[(size_t)(b_off + b)*5 + tid] = o;
  }
}

extern "C" void kernel_launch(void* const* d_in, const int* in_sizes, int n_in,
                              void* d_out, int out_size, void* d_ws, size_t ws_size,
                              hipStream_t stream)
{
  const float* x    = (const float*)d_in[0];
  const float* ln_g = (const float*)d_in[1];
  const float* ln_b = (const float*)d_in[2];
  const float* Wih0 = (const float*)d_in[3];
  const float* Whh0 = (const float*)d_in[4];
  const float* bih0 = (const float*)d_in[5];
  const float* bhh0 = (const float*)d_in[6];
  const float* Wih1 = (const float*)d_in[7];
  const float* Whh1 = (const float*)d_in[8];
  const float* bih1 = (const float*)d_in[9];
  const float* bhh1 = (const float*)d_in[10];
  const float* Wa1  = (const float*)d_in[11];
  const float* ba1  = (const float*)d_in[12];
  const float* Wa2  = (const float*)d_in[13];
  const float* ba2  = (const float*)d_in[14];
  const float* Wf1  = (const float*)d_in[15];
  const float* bf1  = (const float*)d_in[16];
  const float* ln2g = (const float*)d_in[17];
  const float* ln2b = (const float*)d_in[18];
  const float* Wf2  = (const float*)d_in[19];
  const float* bf2  = (const float*)d_in[20];
  float* out = (float*)d_out;

  // wide variants only if spill-free and 2-blocks-per-CU placeable
  bool wide0 = false, wide1 = false;
  {
    hipFuncAttributes fa;
    if (hipFuncGetAttributes(&fa, (const void*)lstm0_wide) == hipSuccess &&
        fa.localSizeBytes == 0 && fa.numRegs <= 256) wide0 = true;
    if (hipFuncGetAttributes(&fa, (const void*)lstm1_wide) == hipSuccess &&
        fa.localSizeBytes == 0 && fa.numRegs <= 256) wide1 = true;
  }

  char* wsb = (char*)d_ws;
  const size_t HBf = (size_t)TT*1024*256*2;   // 134,217,728

  prep_wih1<<<128, 256, 0, stream>>>(Wih1);

  if (ws_size >= 2*HBf){
    uint16_t* h0 = (uint16_t*)wsb;
    uint16_t* h1 = (uint16_t*)(wsb + HBf);

    if (wide0)
      lstm0_wide<<<512, 256, 0, stream>>>(x, ln_g, ln_b, Wih0, Whh0, bih0, bhh0,
                                          h0, 256, 1024, 0);
    else
      lstm0_kernel<<<256, 512, 0, stream>>>(x, ln_g, ln_b, Wih0, Whh0, bih0, bhh0,
                                            h0, 128, 1024, 0);
    if (wide1)
      lstm1_wide<<<512, 256, 0, stream>>>(h0, Whh1, bih1, bhh1, h1, 256, 1024);
    else
      lstm1_kernel<<<256, 512, 0, stream>>>(h0, Whh1, bih1, bhh1, h1, 128, 1024);
    att_kernel  <<<1024, 256, 0, stream>>>(h1, Wa1, ba1, Wa2, ba2, Wf1, bf1,
                                           ln2g, ln2b, Wf2, bf2, out, 1024, 0);
  } else {
    int BR = 512;
    while (BR > 64){
      size_t HB = (size_t)TT*BR*256*2;
      if (2*HB <= ws_size) break;
      BR >>= 1;
    }
    const size_t HB = (size_t)TT*BR*256*2;
    uint16_t* h0 = (uint16_t*)wsb;
    uint16_t* h1 = (uint16_t*)(wsb + HB);

    for (int b_off = 0; b_off < 1024; b_off += BR){
      if (wide0)
        lstm0_wide<<<2*(BR/4), 256, 0, stream>>>(x, ln_g, ln_b, Wih0, Whh0, bih0, bhh0,
                                                 h0, BR/4, BR, b_off);
      else
        lstm0_kernel<<<2*(BR/8), 512, 0, stream>>>(x, ln_g, ln_b, Wih0, Whh0, bih0, bhh0,
                                                   h0, BR/8, BR, b_off);
      if (wide1)
        lstm1_wide<<<2*(BR/4), 256, 0, stream>>>(h0, Whh1, bih1, bhh1, h1, BR/4, BR);
      else
        lstm1_kernel<<<2*(BR/8), 512, 0, stream>>>(h0, Whh1, bih1, bhh1, h1, BR/8, BR);
      att_kernel<<<BR, 256, 0, stream>>>(h1, Wa1, ba1, Wa2, ba2, Wf1, bf1,
                                         ln2g, ln2b, Wf2, bf2, out, BR, b_off);
    }
  }
}

// Round 14
// 723.184 us; speedup vs baseline: 1.6761x; 1.0005x over previous
//
#include <hip/hip_runtime.h>
#include <stdint.h>

#define TT 256
#define NS 8
#define CH 8
#define L2E 1.4426950408889634f
#define L2E2 2.8853900817779268f

typedef __attribute__((ext_vector_type(4))) float f32x4;
typedef __attribute__((ext_vector_type(8))) short s16x8;
typedef __attribute__((ext_vector_type(2))) unsigned int u32x2;

#define DEV static __device__ __forceinline__

// prepped bf16 Wih1 fragments (exp2-scaled): [dir][ntg(32)][kt(8)][lane(64)][8]
__device__ uint16_t g_W1f[2*32*8*64*8];

DEV short f2bf(float f){
  union{float f; uint32_t u;} v; v.f = f;
  uint32_t r = v.u + 0x7fffu + ((v.u>>16)&1u);
  return (short)(r>>16);
}
DEV float bf2f(uint32_t u16){
  union{uint32_t u; float f;} v; v.u = u16<<16; return v.f;
}
DEV uint32_t pk2(float a, float b){
  return (uint32_t)(uint16_t)f2bf(a) | ((uint32_t)(uint16_t)f2bf(b)<<16);
}
DEV float rcpf(float x){ return __builtin_amdgcn_rcpf(x); }
DEV float exp2fast(float x){ return __builtin_amdgcn_exp2f(x); }
DEV float sigm2(float x){ return rcpf(1.f + exp2fast(-x)); }
DEV float tanh2(float x){ return 1.f - 2.f*rcpf(exp2fast(x) + 1.f); }
DEV float tanhr(float x){ return 1.f - 2.f*rcpf(exp2fast(L2E2*x) + 1.f); }
DEV f32x4 MFMA(s16x8 a, s16x8 b, f32x4 c){
  return __builtin_amdgcn_mfma_f32_16x16x32_bf16(a, b, c, 0, 0, 0);
}
DEV s16x8 cvt8(const float* p){
  f32x4 a = *(const f32x4*)p;
  f32x4 b = *(const f32x4*)(p+4);
  s16x8 o;
  o[0]=f2bf(a[0]); o[1]=f2bf(a[1]); o[2]=f2bf(a[2]); o[3]=f2bf(a[3]);
  o[4]=f2bf(b[0]); o[5]=f2bf(b[1]); o[6]=f2bf(b[2]); o[7]=f2bf(b[3]);
  return o;
}
DEV s16x8 cvt8s(const float* p, float s){
  f32x4 a = *(const f32x4*)p;
  f32x4 b = *(const f32x4*)(p+4);
  s16x8 o;
  o[0]=f2bf(a[0]*s); o[1]=f2bf(a[1]*s); o[2]=f2bf(a[2]*s); o[3]=f2bf(a[3]*s);
  o[4]=f2bf(b[0]*s); o[5]=f2bf(b[1]*s); o[6]=f2bf(b[2]*s); o[7]=f2bf(b[3]*s);
  return o;
}
DEV void bar_lds(){
  asm volatile("s_waitcnt lgkmcnt(0)" ::: "memory");
  __builtin_amdgcn_s_barrier();
}

// flush one step's h (8 rows) from a 4KB hbuf frame (512-thr kernels).
DEV void flush_step(const short* hb, uint16_t* __restrict__ hdst, int tp,
                    int dir, int BR, int bg, int tid){
  if (tid < 128){
    int row = tid >> 4, part = tid & 15;
    int tg = dir ? (TT-1-tp) : tp;
    s16x8 v = *(const s16x8*)((const char*)hb + row*256 + (((part ^ row)&15)<<4));
    *(s16x8*)(hdst + ((size_t)tg*BR + bg*NS + row)*256 + dir*128 + part*8) = v;
  }
}
// flush one step's h (4 rows) — 256-thr NS=4 kernels.
DEV void flush_step4(const short* hb, uint16_t* __restrict__ hdst, int tp,
                     int dir, int BR, int bg, int tid){
  if (tid < 64){
    int row = tid >> 4, part = tid & 15;
    int tg = dir ? (TT-1-tp) : tp;
    s16x8 v = *(const s16x8*)((const char*)hb + row*256 + (((part ^ row)&15)<<4));
    *(s16x8*)(hdst + ((size_t)tg*BR + bg*4 + row)*256 + dir*128 + part*8) = v;
  }
}

// ---------------- Wih1 -> bf16 B-fragment layout (exp2-scaled) ----------------
__global__ __launch_bounds__(256) void prep_wih1(const float* __restrict__ Wih1)
{
  int tid = blockIdx.x*256 + threadIdx.x;
  int l = tid & 63, kt = (tid>>6)&7, ntg = (tid>>9)&31, dir = (tid>>14)&1;
  int lm = l&15, lk = l>>4;
  int n = ntg*16 + lm;
  float sc = ((ntg>>3) == 2) ? L2E2 : L2E;
  s16x8 o = cvt8s(Wih1 + ((size_t)(dir*512 + n))*256 + kt*32 + lk*8, sc);
  *(s16x8*)(&g_W1f[(size_t)tid*8]) = o;
}

// ================= narrow (512-thr) lstm0, NS=8 =================
__global__ __launch_bounds__(512,2) void lstm0_kernel(
    const float* __restrict__ x, const float* __restrict__ lng,
    const float* __restrict__ lnb,
    const float* __restrict__ Wih0, const float* __restrict__ Whh0,
    const float* __restrict__ bih0, const float* __restrict__ bhh0,
    uint16_t* __restrict__ h0, int nb, int BR, int b_off)
{
  const int dir = blockIdx.x / nb, bg = blockIdx.x % nb;
  const int tid = threadIdx.x, w = tid>>6, l = tid&63;
  const int lm = l&15, lk = l>>4;
  const int gb = b_off + bg*NS;

  __shared__ short hbuf[2][2048];
  __shared__ short xnbf[TT*NS*8];
  __shared__ short bxs[8*4*64*8];

  for (int i=tid; i<4096; i+=512) ((short*)hbuf)[i] = 0;

  #pragma unroll
  for (int it=0; it<4; ++it){
    int pr = it*512 + tid;
    int r = pr >> 8, t = pr & 255;
    const float* px = x + ((size_t)(gb+r)*TT + t)*6;
    float v[6]; float mu=0.f, var=0.f;
    #pragma unroll
    for (int d=0; d<6; ++d){ v[d]=px[d]; mu+=v[d]; }
    mu *= (1.f/6.f);
    #pragma unroll
    for (int d=0; d<6; ++d){ float dd=v[d]-mu; var+=dd*dd; }
    float rs = rsqrtf(var*(1.f/6.f) + 1e-5f);
    s16x8 vv;
    #pragma unroll
    for (int d=0; d<6; ++d) vv[d] = f2bf((v[d]-mu)*rs*lng[d] + lnb[d]);
    vv[6]=0; vv[7]=0;
    *(s16x8*)&xnbf[(t*NS + r)*8] = vv;
  }

  const int c = w*16 + lm;
  s16x8 bw[4][4];
  float biasc[4];
  #pragma unroll
  for (int G=0; G<4; ++G){
    const float sc = (G==2) ? L2E2 : L2E;
    const int n = G*128 + c;
    biasc[G] = (bih0[dir*512+n] + bhh0[dir*512+n])*sc;
    #pragma unroll
    for (int kt=0; kt<4; ++kt)
      bw[G][kt] = cvt8s(Whh0 + ((size_t)(dir*512+n))*128 + kt*32 + lk*8, sc);
    s16x8 tx;
    #pragma unroll
    for (int j=0; j<8; ++j){
      int k = lk*8 + j;
      tx[j] = (k<6) ? f2bf(Wih0[(size_t)(dir*512+n)*6 + k]*sc) : (short)0;
    }
    *(s16x8*)&bxs[((w*4+G)*64 + l)*8] = tx;
  }

  const int r0 = ((l>>4)&1)*4 + ((l<32)?0:2);
  float cst[2] = {0.f, 0.f};
  __syncthreads();

  for (int t=0; t<TT; ++t){
    const int tt = dir ? (TT-1-t) : t;
    const int rd = t & 1;
    s16x8 ah[4];
    #pragma unroll
    for (int kt=0; kt<4; ++kt){
      int off = rd*4096 + lm*256 + ((kt*64 + lk*16) ^ (lm<<4));
      ah[kt] = *(const s16x8*)((const char*)hbuf + off);
    }
    s16x8 ax = {0,0,0,0,0,0,0,0};
    if (l < 8) ax = *(const s16x8*)&xnbf[(tt*NS + l)*8];

    f32x4 acc[4];
    #pragma unroll
    for (int G=0; G<4; ++G){
      f32x4 a = {0.f,0.f,0.f,0.f};
      #pragma unroll
      for (int kt=0; kt<4; ++kt) a = MFMA(ah[kt], bw[G][kt], a);
      s16x8 bx = *(const s16x8*)&bxs[((w*4+G)*64 + l)*8];
      a = MFMA(ax, bx, a);
      acc[G] = a;
    }

    float g0[4], g1[4];
    #pragma unroll
    for (int G=0; G<4; ++G){
      float o2 = __shfl(acc[G][2], l & 31);
      float o3 = __shfl(acc[G][3], l & 31);
      g0[G] = ((l<32) ? acc[G][0] : o2) + biasc[G];
      g1[G] = ((l<32) ? acc[G][1] : o3) + biasc[G];
    }
    float hv[2];
    {
      float cc = sigm2(g0[1])*cst[0] + sigm2(g0[0])*tanh2(g0[2]);
      cst[0] = cc; hv[0] = sigm2(g0[3])*tanhr(cc);
      cc = sigm2(g1[1])*cst[1] + sigm2(g1[0])*tanh2(g1[2]);
      cst[1] = cc; hv[1] = sigm2(g1[3])*tanhr(cc);
    }

    #pragma unroll
    for (int q=0; q<2; ++q){
      int r = r0 + q;
      *(short*)((char*)hbuf + (rd^1)*4096 + r*256 + ((c*2) ^ (r<<4))) = f2bf(hv[q]);
    }
    if (t > 0)
      flush_step(hbuf[rd], h0, t-1, dir, BR, bg, tid);
    bar_lds();
  }
  flush_step(hbuf[0], h0, TT-1, dir, BR, bg, tid);
}

// ================= narrow (512-thr) lstm1, NS=8, CH=8 =================
__global__ __launch_bounds__(512,2) void lstm1_kernel(
    const uint16_t* __restrict__ h0,
    const float* __restrict__ Whh1, const float* __restrict__ bih1,
    const float* __restrict__ bhh1, uint16_t* __restrict__ h1,
    int nb, int BR)
{
  const int dir = blockIdx.x / nb, bg = blockIdx.x % nb;
  const int tid = threadIdx.x, w = tid>>6, l = tid&63;
  const int lm = l&15, lk = l>>4;

  __shared__ short hbuf[2][2048];
  __shared__ short abuf[2][16384];
  __shared__ u32x2 xpbuf[8192];

  for (int i=tid; i<4096; i+=512) ((short*)hbuf)[i] = 0;

  const int c = w*16 + lm;
  s16x8 bw[4][4];
  float biasv[4];
  #pragma unroll
  for (int G=0; G<4; ++G){
    const float sc = (G==2) ? L2E2 : L2E;
    const int n = G*128 + c;
    biasv[G] = (bih1[dir*512+n] + bhh1[dir*512+n])*sc;
    #pragma unroll
    for (int kt=0; kt<4; ++kt)
      bw[G][kt] = cvt8s(Whh1 + ((size_t)(dir*512+n))*128 + kt*32 + lk*8, sc);
  }

  const int r0 = ((l>>4)&1)*4 + ((l<32)?0:2);
  float cst[2] = {0.f,0.f};
  s16x8 vst[4];

  #pragma unroll
  for (int it=0; it<4; ++it){
    int sid = it*512 + tid, row = sid>>5, sl = sid&31, s = row>>3, b = row&7;
    int tg = dir ? (TT-1-s) : s;
    vst[it] = *(const s16x8*)(h0 + ((size_t)tg*BR + bg*NS + b)*256 + sl*8);
  }
  #pragma unroll
  for (int it=0; it<4; ++it){
    int sid = it*512 + tid, row = sid>>5, sl = sid&31;
    *(s16x8*)((char*)abuf + row*512 + ((sl ^ (row&15))<<4)) = vst[it];
  }
  __syncthreads();

  for (int ch=0; ch<TT/CH; ++ch){
    const int cur = ch & 1;
    const char* ab = (const char*)abuf + cur*32768;

    if (ch < TT/CH-1){
      #pragma unroll
      for (int it=0; it<4; ++it){
        int sid = it*512 + tid, row = sid>>5, sl = sid&31, s = row>>3, b = row&7;
        int ts = (ch+1)*CH + s;
        int tg = dir ? (TT-1-ts) : ts;
        vst[it] = *(const s16x8*)(h0 + ((size_t)tg*BR + bg*NS + b)*256 + sl*8);
      }
    }

    #pragma unroll
    for (int G=0; G<4; ++G){
      f32x4 acc[4];
      #pragma unroll
      for (int mt=0; mt<4; ++mt) acc[mt] = (f32x4){biasv[G],biasv[G],biasv[G],biasv[G]};
      #pragma unroll
      for (int kt=0; kt<8; ++kt){
        s16x8 bfr = *(const s16x8*)(&g_W1f[(((size_t)(dir*32 + G*8 + w)*8 + kt)*64 + l)*8]);
        #pragma unroll
        for (int mt=0; mt<4; ++mt){
          int row = mt*16 + lm;
          s16x8 afr = *(const s16x8*)(ab + row*512 + (((kt*4+lk) ^ (row&15))<<4));
          acc[mt] = MFMA(afr, bfr, acc[mt]);
        }
      }
      #pragma unroll
      for (int mt=0; mt<4; ++mt){
        u32x2 pw;
        pw[0] = pk2(acc[mt][0], acc[mt][1]);
        pw[1] = pk2(acc[mt][2], acc[mt][3]);
        xpbuf[((w*4+G)*4+mt)*64 + l] = pw;
      }
    }

    if (ch < TT/CH-1){
      char* ab2 = (char*)abuf + (cur^1)*32768;
      #pragma unroll
      for (int it=0; it<4; ++it){
        int sid = it*512 + tid, row = sid>>5, sl = sid&31;
        *(s16x8*)(ab2 + row*512 + ((sl ^ (row&15))<<4)) = vst[it];
      }
    }
    bar_lds();

    #pragma unroll
    for (int s=0; s<CH; ++s){
      const int gs = ch*CH + s;
      const int rd = gs & 1;
      const int lane2 = ((((s&1)<<1) + lk)<<4) + lm;

      f32x4 acc4[4];
      #pragma unroll
      for (int G=0; G<4; ++G){
        u32x2 pw = xpbuf[((w*4+G)*4 + (s>>1))*64 + lane2];
        acc4[G] = (f32x4){bf2f(pw[0]&0xffffu), bf2f(pw[0]>>16),
                          bf2f(pw[1]&0xffffu), bf2f(pw[1]>>16)};
      }

      s16x8 ah[4];
      #pragma unroll
      for (int kt=0; kt<4; ++kt){
        int off = rd*4096 + lm*256 + ((kt*64 + lk*16) ^ (lm<<4));
        ah[kt] = *(const s16x8*)((const char*)hbuf + off);
      }
      #pragma unroll
      for (int G=0; G<4; ++G){
        #pragma unroll
        for (int kt=0; kt<4; ++kt)
          acc4[G] = MFMA(ah[kt], bw[G][kt], acc4[G]);
      }

      float g0[4], g1[4];
      #pragma unroll
      for (int G=0; G<4; ++G){
        float o2 = __shfl(acc4[G][2], l & 31);
        float o3 = __shfl(acc4[G][3], l & 31);
        g0[G] = (l<32) ? acc4[G][0] : o2;
        g1[G] = (l<32) ? acc4[G][1] : o3;
      }
      float hv[2];
      float cc = sigm2(g0[1])*cst[0] + sigm2(g0[0])*tanh2(g0[2]);
      cst[0] = cc; hv[0] = sigm2(g0[3])*tanhr(cc);
      cc = sigm2(g1[1])*cst[1] + sigm2(g1[0])*tanh2(g1[2]);
      cst[1] = cc; hv[1] = sigm2(g1[3])*tanhr(cc);

      #pragma unroll
      for (int q=0; q<2; ++q){
        int r = r0 + q;
        *(short*)((char*)hbuf + (rd^1)*4096 + r*256 + ((c*2) ^ (r<<4))) = f2bf(hv[q]);
      }
      if (gs > 0)
        flush_step(hbuf[rd], h1, gs-1, dir, BR, bg, tid);
      bar_lds();
    }
  }
  flush_step(hbuf[0], h1, TT-1, dir, BR, bg, tid);
}

// ================= WIDE lstm0 body: 256 threads, NS=4, 2 col-groups/wave =================
DEV void lstm0_wide_body(char* smem,
    const float* __restrict__ x, const float* __restrict__ lng,
    const float* __restrict__ lnb,
    const float* __restrict__ Wih0, const float* __restrict__ Whh0,
    const float* __restrict__ bih0, const float* __restrict__ bhh0,
    uint16_t* __restrict__ h0, int nb, int BR, int b_off)
{
  const int dir = blockIdx.x / nb, bg = blockIdx.x % nb;
  const int tid = threadIdx.x, w = tid>>6, l = tid&63;
  const int lm = l&15, lk = l>>4;
  const int gb = b_off + bg*4;

  short* hbuf = (short*)smem;             // 8 KB
  short* xnbf = (short*)(smem + 8192);    // 16 KB
  short* bxs  = (short*)(smem + 24576);   // 32 KB

  for (int i=tid; i<4096; i+=256) hbuf[i] = 0;

  #pragma unroll
  for (int it=0; it<4; ++it){
    int pr = it*256 + tid;
    int r = pr >> 8, t = pr & 255;
    const float* px = x + ((size_t)(gb+r)*TT + t)*6;
    float v[6]; float mu=0.f, var=0.f;
    #pragma unroll
    for (int d=0; d<6; ++d){ v[d]=px[d]; mu+=v[d]; }
    mu *= (1.f/6.f);
    #pragma unroll
    for (int d=0; d<6; ++d){ float dd=v[d]-mu; var+=dd*dd; }
    float rs = rsqrtf(var*(1.f/6.f) + 1e-5f);
    s16x8 vv;
    #pragma unroll
    for (int d=0; d<6; ++d) vv[d] = f2bf((v[d]-mu)*rs*lng[d] + lnb[d]);
    vv[6]=0; vv[7]=0;
    *(s16x8*)&xnbf[(t*4 + r)*8] = vv;
  }

  int cc2[2];
  s16x8 bw[2][4][4];
  float biasc[2][4];
  #pragma unroll
  for (int cg=0; cg<2; ++cg){
    const int cgid = w + cg*4;
    const int c = cgid*16 + lm;
    cc2[cg] = c;
    #pragma unroll
    for (int G=0; G<4; ++G){
      const float sc = (G==2) ? L2E2 : L2E;
      const int n = G*128 + c;
      biasc[cg][G] = (bih0[dir*512+n] + bhh0[dir*512+n])*sc;
      #pragma unroll
      for (int kt=0; kt<4; ++kt)
        bw[cg][G][kt] = cvt8s(Whh0 + ((size_t)(dir*512+n))*128 + kt*32 + lk*8, sc);
      s16x8 tx;
      #pragma unroll
      for (int j=0; j<8; ++j){
        int k = lk*8 + j;
        tx[j] = (k<6) ? f2bf(Wih0[(size_t)(dir*512+n)*6 + k]*sc) : (short)0;
      }
      *(s16x8*)&bxs[((cgid*4+G)*64 + l)*8] = tx;
    }
  }

  const int r0 = ((l>>4)&1)*4 + ((l<32)?0:2);
  float cst[2][2] = {{0.f,0.f},{0.f,0.f}};
  __syncthreads();

  for (int t=0; t<TT; ++t){
    const int tt = dir ? (TT-1-t) : t;
    const int rd = t & 1;
    s16x8 ah[4];
    #pragma unroll
    for (int kt=0; kt<4; ++kt){
      int off = rd*4096 + lm*256 + ((kt*64 + lk*16) ^ (lm<<4));
      ah[kt] = *(const s16x8*)((const char*)hbuf + off);
    }
    s16x8 ax = {0,0,0,0,0,0,0,0};
    if (l < 4) ax = *(const s16x8*)&xnbf[(tt*4 + l)*8];

    #pragma unroll
    for (int cg=0; cg<2; ++cg){
      const int cgid = w + cg*4;
      f32x4 acc[4];
      #pragma unroll
      for (int G=0; G<4; ++G){
        f32x4 a = {0.f,0.f,0.f,0.f};
        #pragma unroll
        for (int kt=0; kt<4; ++kt) a = MFMA(ah[kt], bw[cg][G][kt], a);
        s16x8 bx = *(const s16x8*)&bxs[((cgid*4+G)*64 + l)*8];
        a = MFMA(ax, bx, a);
        acc[G] = a;
      }
      float g0[4], g1[4];
      #pragma unroll
      for (int G=0; G<4; ++G){
        float o2 = __shfl(acc[G][2], l & 31);
        float o3 = __shfl(acc[G][3], l & 31);
        g0[G] = ((l<32) ? acc[G][0] : o2) + biasc[cg][G];
        g1[G] = ((l<32) ? acc[G][1] : o3) + biasc[cg][G];
      }
      float c0 = sigm2(g0[1])*cst[cg][0] + sigm2(g0[0])*tanh2(g0[2]);
      cst[cg][0] = c0;
      float hv0 = sigm2(g0[3])*tanhr(c0);
      float c1 = sigm2(g1[1])*cst[cg][1] + sigm2(g1[0])*tanh2(g1[2]);
      cst[cg][1] = c1;
      float hv1 = sigm2(g1[3])*tanhr(c1);

      if (r0 < 4){
        const int c = cc2[cg];
        *(short*)((char*)hbuf + (rd^1)*4096 + r0*256 + ((c*2) ^ (r0<<4))) = f2bf(hv0);
        int r = r0+1;
        *(short*)((char*)hbuf + (rd^1)*4096 + r*256 + ((c*2) ^ (r<<4))) = f2bf(hv1);
      }
    }
    if (t > 0)
      flush_step4(hbuf + rd*2048, h0, t-1, dir, BR, bg, tid);
    bar_lds();
  }
  flush_step4(hbuf, h0, TT-1, dir, BR, bg, tid);
}

__global__ __launch_bounds__(256,2) void lstm0_wide_a(
    const float* x, const float* lng, const float* lnb,
    const float* Wih0, const float* Whh0, const float* bih0, const float* bhh0,
    uint16_t* h0, int nb, int BR, int b_off)
{
  __shared__ char smem[57344];
  lstm0_wide_body(smem, x, lng, lnb, Wih0, Whh0, bih0, bhh0, h0, nb, BR, b_off);
}
__global__ __launch_bounds__(256,1) void lstm0_wide_b(
    const float* x, const float* lng, const float* lnb,
    const float* Wih0, const float* Whh0, const float* bih0, const float* bhh0,
    uint16_t* h0, int nb, int BR, int b_off)
{
  __shared__ char smem[57344];
  lstm0_wide_body(smem, x, lng, lnb, Wih0, Whh0, bih0, bhh0, h0, nb, BR, b_off);
}

// ================= WIDE lstm1 body: 256 threads, NS=4, CH=8 =================
DEV void lstm1_wide_body(char* smem,
    const uint16_t* __restrict__ h0,
    const float* __restrict__ Whh1, const float* __restrict__ bih1,
    const float* __restrict__ bhh1, uint16_t* __restrict__ h1,
    int nb, int BR)
{
  const int dir = blockIdx.x / nb, bg = blockIdx.x % nb;
  const int tid = threadIdx.x, w = tid>>6, l = tid&63;
  const int lm = l&15, lk = l>>4;

  short* hbuf = (short*)smem;                 // 8 KB
  short* abuf = (short*)(smem + 8192);        // 32 KB (2 x 16KB)
  u32x2* xpbuf = (u32x2*)(smem + 40960);      // 32 KB

  for (int i=tid; i<4096; i+=256) hbuf[i] = 0;

  int cc2[2];
  s16x8 bw[2][4][4];
  float biasv[2][4];
  #pragma unroll
  for (int cg=0; cg<2; ++cg){
    const int c = (w + cg*4)*16 + lm;
    cc2[cg] = c;
    #pragma unroll
    for (int G=0; G<4; ++G){
      const float sc = (G==2) ? L2E2 : L2E;
      const int n = G*128 + c;
      biasv[cg][G] = (bih1[dir*512+n] + bhh1[dir*512+n])*sc;
      #pragma unroll
      for (int kt=0; kt<4; ++kt)
        bw[cg][G][kt] = cvt8s(Whh1 + ((size_t)(dir*512+n))*128 + kt*32 + lk*8, sc);
    }
  }

  const int r0 = ((l>>4)&1)*4 + ((l<32)?0:2);
  float cst[2][2] = {{0.f,0.f},{0.f,0.f}};
  s16x8 vst[4];

  #pragma unroll
  for (int it=0; it<4; ++it){
    int sid = it*256 + tid, row = sid>>5, sl = sid&31, s = row>>2, b = row&3;
    int tg = dir ? (TT-1-s) : s;
    vst[it] = *(const s16x8*)(h0 + ((size_t)tg*BR + bg*4 + b)*256 + sl*8);
  }
  #pragma unroll
  for (int it=0; it<4; ++it){
    int sid = it*256 + tid, row = sid>>5, sl = sid&31;
    *(s16x8*)((char*)abuf + row*512 + ((sl ^ (row&15))<<4)) = vst[it];
  }
  __syncthreads();

  for (int ch=0; ch<TT/CH; ++ch){
    const int cur = ch & 1;
    const char* ab = (const char*)abuf + cur*16384;

    if (ch < TT/CH-1){
      #pragma unroll
      for (int it=0; it<4; ++it){
        int sid = it*256 + tid, row = sid>>5, sl = sid&31, s = row>>2, b = row&3;
        int ts = (ch+1)*CH + s;
        int tg = dir ? (TT-1-ts) : ts;
        vst[it] = *(const s16x8*)(h0 + ((size_t)tg*BR + bg*4 + b)*256 + sl*8);
      }
    }

    // phase A
    #pragma unroll
    for (int cg=0; cg<2; ++cg){
      const int cgid = w + cg*4;
      #pragma unroll
      for (int G=0; G<4; ++G){
        f32x4 acc[2];
        #pragma unroll
        for (int mt=0; mt<2; ++mt)
          acc[mt] = (f32x4){biasv[cg][G],biasv[cg][G],biasv[cg][G],biasv[cg][G]};
        #pragma unroll
        for (int kt=0; kt<8; ++kt){
          s16x8 bfr = *(const s16x8*)(&g_W1f[(((size_t)(dir*32 + G*8 + cgid)*8 + kt)*64 + l)*8]);
          #pragma unroll
          for (int mt=0; mt<2; ++mt){
            int row = mt*16 + lm;
            s16x8 afr = *(const s16x8*)(ab + row*512 + (((kt*4+lk) ^ (row&15))<<4));
            acc[mt] = MFMA(afr, bfr, acc[mt]);
          }
        }
        #pragma unroll
        for (int mt=0; mt<2; ++mt){
          u32x2 pw;
          pw[0] = pk2(acc[mt][0], acc[mt][1]);
          pw[1] = pk2(acc[mt][2], acc[mt][3]);
          xpbuf[((cgid*4+G)*2+mt)*64 + l] = pw;
        }
      }
    }

    if (ch < TT/CH-1){
      char* ab2 = (char*)abuf + (cur^1)*16384;
      #pragma unroll
      for (int it=0; it<4; ++it){
        int sid = it*256 + tid, row = sid>>5, sl = sid&31;
        *(s16x8*)(ab2 + row*512 + ((sl ^ (row&15))<<4)) = vst[it];
      }
    }
    bar_lds();

    // phase B
    #pragma unroll
    for (int s=0; s<CH; ++s){
      const int gs = ch*CH + s;
      const int rd = gs & 1;
      const int lane2 = ((s&3)<<4) + lm;
      const int mt = s>>2;

      s16x8 ah[4];
      #pragma unroll
      for (int kt=0; kt<4; ++kt){
        int off = rd*4096 + lm*256 + ((kt*64 + lk*16) ^ (lm<<4));
        ah[kt] = *(const s16x8*)((const char*)hbuf + off);
      }

      #pragma unroll
      for (int cg=0; cg<2; ++cg){
        const int cgid = w + cg*4;
        f32x4 acc4[4];
        #pragma unroll
        for (int G=0; G<4; ++G){
          u32x2 pw = xpbuf[((cgid*4+G)*2 + mt)*64 + lane2];
          acc4[G] = (f32x4){bf2f(pw[0]&0xffffu), bf2f(pw[0]>>16),
                            bf2f(pw[1]&0xffffu), bf2f(pw[1]>>16)};
          #pragma unroll
          for (int kt=0; kt<4; ++kt)
            acc4[G] = MFMA(ah[kt], bw[cg][G][kt], acc4[G]);
        }

        float g0[4], g1[4];
        #pragma unroll
        for (int G=0; G<4; ++G){
          float o2 = __shfl(acc4[G][2], l & 31);
          float o3 = __shfl(acc4[G][3], l & 31);
          g0[G] = (l<32) ? acc4[G][0] : o2;
          g1[G] = (l<32) ? acc4[G][1] : o3;
        }
        float c0 = sigm2(g0[1])*cst[cg][0] + sigm2(g0[0])*tanh2(g0[2]);
        cst[cg][0] = c0;
        float hv0 = sigm2(g0[3])*tanhr(c0);
        float c1 = sigm2(g1[1])*cst[cg][1] + sigm2(g1[0])*tanh2(g1[2]);
        cst[cg][1] = c1;
        float hv1 = sigm2(g1[3])*tanhr(c1);

        if (r0 < 4){
          const int c = cc2[cg];
          *(short*)((char*)hbuf + (rd^1)*4096 + r0*256 + ((c*2) ^ (r0<<4))) = f2bf(hv0);
          int r = r0+1;
          *(short*)((char*)hbuf + (rd^1)*4096 + r*256 + ((c*2) ^ (r<<4))) = f2bf(hv1);
        }
      }
      if (gs > 0)
        flush_step4(hbuf + rd*2048, h1, gs-1, dir, BR, bg, tid);
      bar_lds();
    }
  }
  flush_step4(hbuf, h1, TT-1, dir, BR, bg, tid);
}

__global__ __launch_bounds__(256,2) void lstm1_wide_a(
    const uint16_t* h0, const float* Whh1, const float* bih1,
    const float* bhh1, uint16_t* h1, int nb, int BR)
{
  __shared__ char smem[73728];
  lstm1_wide_body(smem, h0, Whh1, bih1, bhh1, h1, nb, BR);
}
__global__ __launch_bounds__(256,1) void lstm1_wide_b(
    const uint16_t* h0, const float* Whh1, const float* bih1,
    const float* bhh1, uint16_t* h1, int nb, int BR)
{
  __shared__ char smem[73728];
  lstm1_wide_body(smem, h0, Whh1, bih1, bhh1, h1, nb, BR);
}

// ========== fused attention: scores + softmax + context + LN head ==========
__global__ __launch_bounds__(256,2) void att_kernel(
    const uint16_t* __restrict__ h1,
    const float* __restrict__ Wa1, const float* __restrict__ ba1,
    const float* __restrict__ Wa2, const float* __restrict__ ba2,
    const float* __restrict__ Wf1, const float* __restrict__ bf1,
    const float* __restrict__ lg, const float* __restrict__ lb,
    const float* __restrict__ Wf2, const float* __restrict__ bf2v,
    float* __restrict__ out, int BR, int b_off)
{
  const int b = blockIdx.x;
  const int tid = threadIdx.x, w = tid>>6, l = tid&63;
  const int lm = l&15, lk = l>>4;

  __shared__ short abuf[64*256];
  __shared__ float sbuf[TT];
  __shared__ float scred[4][64];
  __shared__ float red[8];
  __shared__ float cbuf[256];
  __shared__ float zb[128];

  s16x8 bwa[2][8]; float b1v[2], wa2v[2];
  #pragma unroll
  for (int nt=0; nt<2; ++nt){
    int n = w*32 + nt*16 + lm;
    b1v[nt] = ba1[n]; wa2v[nt] = Wa2[n];
    #pragma unroll
    for (int kt=0; kt<8; ++kt)
      bwa[nt][kt] = cvt8(Wa1 + (size_t)n*256 + kt*32 + lk*8);
  }

  for (int tb=0; tb<4; ++tb){
    const int t0 = tb*64;
    __syncthreads();
    #pragma unroll
    for (int it=0; it<8; ++it){
      int sid = it*256 + tid, row = sid>>5, sl = sid&31;
      s16x8 v = *(const s16x8*)(h1 + ((size_t)(t0+row)*BR + b)*256 + sl*8);
      *(s16x8*)((char*)abuf + row*512 + ((sl ^ (row&15))<<4)) = v;
    }
    __syncthreads();

    #pragma unroll
    for (int mt=0; mt<4; ++mt){
      f32x4 a0 = {b1v[0],b1v[0],b1v[0],b1v[0]};
      f32x4 a1 = {b1v[1],b1v[1],b1v[1],b1v[1]};
      #pragma unroll
      for (int kt=0; kt<8; ++kt){
        int row = mt*16 + lm;
        s16x8 af = *(const s16x8*)((const char*)abuf + row*512 + (((kt*4+lk) ^ (row&15))<<4));
        a0 = MFMA(af, bwa[0][kt], a0);
        a1 = MFMA(af, bwa[1][kt], a1);
      }
      #pragma unroll
      for (int j=0; j<4; ++j){
        float pj = tanhr(a0[j])*wa2v[0] + tanhr(a1[j])*wa2v[1];
        #pragma unroll
        for (int m2=1; m2<16; m2<<=1) pj += __shfl_xor(pj, m2);
        if (lm == 0) scred[w][mt*16 + lk*4 + j] = pj;
      }
    }
    __syncthreads();
    if (tid < 64)
      sbuf[t0 + tid] = scred[0][tid]+scred[1][tid]+scred[2][tid]+scred[3][tid] + ba2[0];
  }
  __syncthreads();

  float scv = sbuf[tid];
  float m = scv;
  #pragma unroll
  for (int d=1; d<64; d<<=1) m = fmaxf(m, __shfl_xor(m, d));
  if (l == 0) red[w] = m;
  __syncthreads();
  m = fmaxf(fmaxf(red[0],red[1]), fmaxf(red[2],red[3]));
  float e = exp2fast(L2E*(scv - m));
  float ssum = e;
  #pragma unroll
  for (int d=1; d<64; d<<=1) ssum += __shfl_xor(ssum, d);
  if (l == 0) red[4+w] = ssum;
  __syncthreads();
  ssum = red[4]+red[5]+red[6]+red[7];
  sbuf[tid] = e * rcpf(ssum);
  __syncthreads();

  float acc = 0.f;
  const uint16_t* hp = h1 + (size_t)b*256 + tid;
  #pragma unroll 8
  for (int t2=0; t2<TT; ++t2) acc += sbuf[t2] * bf2f(hp[(size_t)t2*BR*256]);
  cbuf[tid] = acc;
  __syncthreads();

  float y = 0.f;
  if (tid < 128){
    y = bf1[tid];
    const float* wr = Wf1 + (size_t)tid*256;
    #pragma unroll 8
    for (int k=0; k<256; ++k) y += cbuf[k]*wr[k];
  }
  float s2 = y;
  #pragma unroll
  for (int d=1; d<64; d<<=1) s2 += __shfl_xor(s2, d);
  if (l == 0) red[w] = s2;
  __syncthreads();
  float mu = (red[0]+red[1]+red[2]+red[3])*(1.f/128.f);
  float dv = y - mu;
  float q = (tid < 128) ? dv*dv : 0.f;
  #pragma unroll
  for (int d=1; d<64; d<<=1) q += __shfl_xor(q, d);
  if (l == 0) red[4+w] = q;
  __syncthreads();
  float var = (red[4]+red[5]+red[6]+red[7])*(1.f/128.f);
  if (tid < 128){
    float z = dv*rsqrtf(var + 1e-5f)*lg[tid] + lb[tid];
    zb[tid] = fmaxf(z, 0.f);
  }
  __syncthreads();
  if (tid < 5){
    float o = bf2v[tid];
    const float* wp = Wf2 + (size_t)tid*128;
    for (int k=0; k<128; ++k) o += zb[k]*wp[k];
    out[(size_t)(b_off + b)*5 + tid] = o;
  }
}

extern "C" void kernel_launch(void* const* d_in, const int* in_sizes, int n_in,
                              void* d_out, int out_size, void* d_ws, size_t ws_size,
                              hipStream_t stream)
{
  const float* x    = (const float*)d_in[0];
  const float* ln_g = (const float*)d_in[1];
  const float* ln_b = (const float*)d_in[2];
  const float* Wih0 = (const float*)d_in[3];
  const float* Whh0 = (const float*)d_in[4];
  const float* bih0 = (const float*)d_in[5];
  const float* bhh0 = (const float*)d_in[6];
  const float* Wih1 = (const float*)d_in[7];
  const float* Whh1 = (const float*)d_in[8];
  const float* bih1 = (const float*)d_in[9];
  const float* bhh1 = (const float*)d_in[10];
  const float* Wa1  = (const float*)d_in[11];
  const float* ba1  = (const float*)d_in[12];
  const float* Wa2  = (const float*)d_in[13];
  const float* ba2  = (const float*)d_in[14];
  const float* Wf1  = (const float*)d_in[15];
  const float* bf1  = (const float*)d_in[16];
  const float* ln2g = (const float*)d_in[17];
  const float* ln2b = (const float*)d_in[18];
  const float* Wf2  = (const float*)d_in[19];
  const float* bf2  = (const float*)d_in[20];
  float* out = (float*)d_out;

  auto ok = [](const void* f) -> bool {
    hipFuncAttributes fa;
    if (hipFuncGetAttributes(&fa, f) != hipSuccess) return false;
    return fa.localSizeBytes == 0 && fa.numRegs <= 256;
  };
  const int v0 = ok((const void*)lstm0_wide_a) ? 1 : (ok((const void*)lstm0_wide_b) ? 2 : 0);
  const int v1 = ok((const void*)lstm1_wide_a) ? 1 : (ok((const void*)lstm1_wide_b) ? 2 : 0);

  char* wsb = (char*)d_ws;
  const size_t HBf = (size_t)TT*1024*256*2;   // 134,217,728

  prep_wih1<<<128, 256, 0, stream>>>(Wih1);

  auto run = [&](uint16_t* h0, uint16_t* h1, int BR, int b_off){
    if (v0 == 1)
      lstm0_wide_a<<<2*(BR/4), 256, 0, stream>>>(x, ln_g, ln_b, Wih0, Whh0, bih0, bhh0,
                                                 h0, BR/4, BR, b_off);
    else if (v0 == 2)
      lstm0_wide_b<<<2*(BR/4), 256, 0, stream>>>(x, ln_g, ln_b, Wih0, Whh0, bih0, bhh0,
                                                 h0, BR/4, BR, b_off);
    else
      lstm0_kernel<<<2*(BR/8), 512, 0, stream>>>(x, ln_g, ln_b, Wih0, Whh0, bih0, bhh0,
                                                 h0, BR/8, BR, b_off);
    if (v1 == 1)
      lstm1_wide_a<<<2*(BR/4), 256, 0, stream>>>(h0, Whh1, bih1, bhh1, h1, BR/4, BR);
    else if (v1 == 2)
      lstm1_wide_b<<<2*(BR/4), 256, 0, stream>>>(h0, Whh1, bih1, bhh1, h1, BR/4, BR);
    else
      lstm1_kernel<<<2*(BR/8), 512, 0, stream>>>(h0, Whh1, bih1, bhh1, h1, BR/8, BR);
    att_kernel<<<BR, 256, 0, stream>>>(h1, Wa1, ba1, Wa2, ba2, Wf1, bf1,
                                       ln2g, ln2b, Wf2, bf2, out, BR, b_off);
  };

  if (ws_size >= 2*HBf){
    uint16_t* h0 = (uint16_t*)wsb;
    uint16_t* h1 = (uint16_t*)(wsb + HBf);
    run(h0, h1, 1024, 0);
  } else {
    int BR = 512;
    while (BR > 64){
      size_t HB = (size_t)TT*BR*256*2;
      if (2*HB <= ws_size) break;
      BR >>= 1;
    }
    const size_t HB = (size_t)TT*BR*256*2;
    uint16_t* h0 = (uint16_t*)wsb;
    uint16_t* h1 = (uint16_t*)(wsb + HB);
    for (int b_off = 0; b_off < 1024; b_off += BR)
      run(h0, h1, BR, b_off);
  }
}